// Round 6
// baseline (430.853 us; speedup 1.0000x reference)
//
#include <hip/hip_runtime.h>
#include <stdint.h>

#define USER_NUM 100000
#define ITEM_NUM 50000
#define N_NODES  150000
#define HIDE_DIM 64
#define N_EDGES  4000000
#define SLAB     72   // max in-degree slab; prior rounds passed (no clipping at 72)

// ---- out-degree histogram (atomic-free, 8-bit packed LDS bins) ----
#define HRANGES 3
#define RNODES  50000
#define RWORDS  (RNODES / 4)
#define SLICES  128                    // 4M % 128 == 0 -> EPS exact
#define EPS     (N_EDGES / SLICES)     // 31250

// ---- bucket sort by dst ----
#define BSH     9
#define BNODES  512
#define NBUCK   293                    // ceil(150000/512)
#define SSLICES 640                    // LDS-staged scatter: slice = 6250 edges
#define EPSB    (N_EDGES / SSLICES)    // 6250, exact

// ---- bf16 helpers ----
__device__ __forceinline__ unsigned short f2bf(float f) {
    union { float f; unsigned int i; } c; c.f = f;
    unsigned int b = c.i;
    return (unsigned short)((b + 0x7FFFu + ((b >> 16) & 1u)) >> 16);
}
__device__ __forceinline__ float lo_bf(uint32_t u) {
    union { uint32_t u; float f; } c; c.u = u << 16; return c.f;
}
__device__ __forceinline__ float hi_bf(uint32_t u) {
    union { uint32_t u; float f; } c; c.u = u & 0xffff0000u; return c.f;
}

// ---------------- fused histograms ----------------
// blocks r in [0,3): out-degree partial hist of src for node range r (8-bit packed LDS bins)
// blocks r == 3   : dst bucket-total hist -> global atomicAdd into btot (37.5k atomics)
__global__ void histfused_kernel(const int* __restrict__ src, const int* __restrict__ dst,
                                 uint32_t* __restrict__ partial, uint32_t* __restrict__ btot) {
    __shared__ uint32_t bins[RWORDS];   // 50 KB; r==3 uses first NBUCK words
    int r  = blockIdx.x / SLICES;
    int sl = blockIdx.x - r * SLICES;
    int e0 = sl * EPS, e1 = e0 + EPS;   // exact slicing
    if (r < HRANGES) {
        for (int i = threadIdx.x; i < RWORDS; i += 512) bins[i] = 0;
        __syncthreads();
        int lo = r * RNODES, hi = lo + RNODES;
        for (int e = e0 + threadIdx.x; e < e1; e += 512) {
            int s = src[e];
            if (s >= lo && s < hi) {
                int x = s - lo;
                atomicAdd(&bins[x >> 2], 1u << (8 * (x & 3)));
            }
        }
        __syncthreads();
        uint32_t* out = partial + (size_t)(r * SLICES + sl) * RWORDS;
        for (int i = threadIdx.x; i < RWORDS; i += 512) out[i] = bins[i];
    } else {
        for (int i = threadIdx.x; i < NBUCK; i += 512) bins[i] = 0;
        __syncthreads();
        for (int e = e0 + threadIdx.x; e < e1; e += 512)
            atomicAdd(&bins[((unsigned)dst[e]) >> BSH], 1u);
        __syncthreads();
        for (int i = threadIdx.x; i < NBUCK; i += 512)
            if (bins[i]) atomicAdd(&btot[i], bins[i]);
    }
}

// ---------------- reduce out-degree partials -> out_norm directly ----------------
// Packed u32 summation is carry-safe: each byte column sums to the node's total
// out-degree <= ~65 < 256.
__global__ void rednorm_kernel(const uint32_t* __restrict__ partial, float* __restrict__ out_norm) {
    int g = blockIdx.x * blockDim.x + threadIdx.x;
    if (g >= HRANGES * RWORDS) return;
    int r = g / RWORDS, w = g - r * RWORDS;
    const uint32_t* p = partial + (size_t)r * SLICES * RWORDS + w;
    uint32_t acc = 0;
#pragma unroll 16
    for (int sl = 0; sl < SLICES; ++sl) acc += p[(size_t)sl * RWORDS];
    int oc0 = acc & 255, oc1 = (acc >> 8) & 255, oc2 = (acc >> 16) & 255, oc3 = (acc >> 24);
    float4 o;
    o.x = 1.0f / sqrtf((float)(oc0 < 1 ? 1 : oc0));
    o.y = 1.0f / sqrtf((float)(oc1 < 1 ? 1 : oc1));
    o.z = 1.0f / sqrtf((float)(oc2 < 1 ? 1 : oc2));
    o.w = 1.0f / sqrtf((float)(oc3 < 1 ? 1 : oc3));
    ((float4*)out_norm)[(size_t)r * (RNODES / 4) + w] = o;
}

// ---------------- scatter v5: LDS-staged; self-scanned btot; runs reserved via gcur ----------------
// No scanB/bbase: each block scans btot (293 entries) in LDS to get bucket bases, then
// reserves its per-bucket runs with one atomicAdd on gcur[b] (gcur starts at 0).
__global__ void scatter_kernel(const int* __restrict__ src, const int* __restrict__ dst,
                               const uint32_t* __restrict__ btot, uint32_t* __restrict__ gcur,
                               uint32_t* __restrict__ sorted) {
    __shared__ uint32_t cnt[NBUCK];    // counts -> then local cursor
    __shared__ uint32_t excl[NBUCK];   // local exclusive scan
    __shared__ uint32_t bex[NBUCK];    // global bucket base (excl scan of btot)
    __shared__ uint32_t gpos0[NBUCK];  // reserved global run start per bucket
    __shared__ uint32_t sarr[512];     // scan workspace
    __shared__ uint32_t sval[EPSB];    // staged packed values, bucket-grouped (25 KB)
    __shared__ uint16_t sbkt[EPSB];    // bucket id per staged entry (12.5 KB)

    int s = blockIdx.x;
    int t = threadIdx.x;
    for (int i = t; i < NBUCK; i += 512) cnt[i] = 0;

    // scan btot -> bucket bases
    uint32_t bv = (t < NBUCK) ? btot[t] : 0;
    sarr[t] = bv;
    __syncthreads();
    for (int off = 1; off < 512; off <<= 1) {
        uint32_t x = (t >= off) ? sarr[t - off] : 0;
        __syncthreads();
        sarr[t] += x;
        __syncthreads();
    }
    if (t < NBUCK) bex[t] = sarr[t] - bv;
    __syncthreads();

    int e0 = s * EPSB;
    // pass 1: count
    for (int e = e0 + t; e < e0 + EPSB; e += 512)
        atomicAdd(&cnt[((unsigned)dst[e]) >> BSH], 1u);
    __syncthreads();

    // local inclusive scan over 293 counts (Hillis-Steele on 512 slots)
    uint32_t myc = (t < NBUCK) ? cnt[t] : 0;
    sarr[t] = myc;
    __syncthreads();
    for (int off = 1; off < 512; off <<= 1) {
        uint32_t x = (t >= off) ? sarr[t - off] : 0;
        __syncthreads();
        sarr[t] += x;
        __syncthreads();
    }
    if (t < NBUCK) {
        uint32_t ex = sarr[t] - myc;
        excl[t] = ex;
        cnt[t] = ex;                                             // local cursor starts at excl
        if (myc) gpos0[t] = bex[t] + atomicAdd(&gcur[t], myc);   // reserve contiguous run
    }
    __syncthreads();

    // pass 2: place into LDS grouped by bucket, tag with bucket id
    for (int e = e0 + t; e < e0 + EPSB; e += 512) {
        unsigned d = (unsigned)dst[e];
        int sv = src[e];
        unsigned b = d >> BSH;
        unsigned nib = d & (BNODES - 1);
        uint32_t r = atomicAdd(&cnt[b], 1u);
        sval[r] = (uint32_t)sv | (nib << 18);
        sbkt[r] = (uint16_t)b;
    }
    __syncthreads();

    // pass 3: stream out (coalesced within bucket runs)
    for (int i = t; i < EPSB; i += 512) {
        unsigned b = sbkt[i];
        sorted[gpos0[b] + ((uint32_t)i - excl[b])] = sval[i];
    }
}

// ---------------- slab: per-bucket slab placement + in-degree/in_norm (1024 thr) ----------------
// Self-scans btot for (start, n); 1024 threads halve block time -> halves the 293/256 tail.
__global__ void slab_kernel(const uint32_t* __restrict__ sorted, const uint32_t* __restrict__ btot,
                            int* __restrict__ esrc, int* __restrict__ in_cnt,
                            float* __restrict__ in_norm) {
    __shared__ uint32_t cur[BNODES];
    __shared__ uint32_t sarr[512];
    int b = blockIdx.x;
    int t = threadIdx.x;
    if (t < BNODES) cur[t] = 0;

    // scan btot -> this bucket's start/n (all threads hit the syncs)
    uint32_t bv = 0;
    if (t < 512) { bv = (t < NBUCK) ? btot[t] : 0; sarr[t] = bv; }
    __syncthreads();
    for (int off = 1; off < 512; off <<= 1) {
        uint32_t x = 0;
        if (t < 512 && t >= off) x = sarr[t - off];
        __syncthreads();
        if (t < 512) sarr[t] += x;
        __syncthreads();
    }
    uint32_t start = sarr[b] - btot[b];   // exclusive scan value at b
    uint32_t n = btot[b];

    for (uint32_t i = t; i < n; i += 1024) {
        uint32_t v = sorted[start + i];
        uint32_t nib = v >> 18;
        uint32_t sc = v & 0x3FFFFu;
        uint32_t r = atomicAdd(&cur[nib], 1u);
        if (r < SLAB) esrc[((size_t)(b << BSH) + nib) * SLAB + r] = (int)sc;
    }
    __syncthreads();
    if (t < BNODES) {
        int node = (b << BSH) + t;
        if (node < N_NODES) {
            int ic = (int)cur[t];
            in_cnt[node] = ic;
            if (ic < 1) ic = 1;
            in_norm[node] = 1.0f / sqrtf((float)ic);
        }
    }
}

// ---------------- init: h0 = bf16(x * out_norm), packed u32 ----------------
__global__ void init_kernel(const float2* __restrict__ user2, const float2* __restrict__ item2,
                            const float* __restrict__ out_norm, uint32_t* __restrict__ h0) {
    int gid = blockIdx.x * blockDim.x + threadIdx.x;
    if (gid >= N_NODES * 32) return;
    int node = gid >> 5;
    float2 v = (node < USER_NUM) ? user2[gid] : item2[gid - USER_NUM * 32];
    float on = out_norm[node];
    h0[gid] = (uint32_t)f2bf(v.x * on) | ((uint32_t)f2bf(v.y * on) << 16);
}

// ---------------- gather aggregation v9 (core FROZEN at L2 request-rate ceiling) ----------------
// lane = (half = node [bit5], p = edge parity [bits3-4], q = 16B col [bits0-2]).
// mode 0 (L0, L1): hn = pack(emb*on)                       [pure pack, no res traffic]
// mode 1 (L2/final): res = x + (h1_own*s1 + h2_own*s2)*rinv + e3*s3
__global__ void agg_kernel(const uint32_t* __restrict__ h32, const int* __restrict__ esrc,
                           const int* __restrict__ in_cnt,
                           const float* __restrict__ in_norm, const float* __restrict__ out_norm,
                           const float4* __restrict__ user4, const float4* __restrict__ item4,
                           float4* __restrict__ res4, uint4* __restrict__ hn128,
                           const uint2* __restrict__ h1own,
                           float s1, float s2, float s3, int mode) {
    int wid  = (blockIdx.x * blockDim.x + threadIdx.x) >> 6;
    int lane = threadIdx.x & 63;
    int half = lane >> 5;
    int p    = (lane >> 3) & 3;
    int q    = lane & 7;
    int node = wid * 2 + half;
    if (node >= N_NODES) return;

    int deg = in_cnt[node]; if (deg > SLAB) deg = SLAB;
    int beg = node * SLAB;
    int hb  = half << 5;

    // half-lane l holds edge l in idx0 and edge 32+l in idx1 (masked to 0 if OOR)
    int sl0 = lane & 31;
    int idx0 = (sl0      < deg) ? esrc[beg + sl0]      : 0;
    int idx1 = (sl0 + 32 < deg) ? esrc[beg + sl0 + 32] : 0;

    const uint4* h128 = (const uint4*)h32;   // 8 x uint4 per node (128B)

    float a0 = 0.f, a1 = 0.f, a2 = 0.f, a3 = 0.f;
    float a4 = 0.f, a5 = 0.f, a6 = 0.f, a7 = 0.f;

#define ACC8(U) do { \
        a0 += lo_bf((U).x); a1 += hi_bf((U).x); \
        a2 += lo_bf((U).y); a3 += hi_bf((U).y); \
        a4 += lo_bf((U).z); a5 += hi_bf((U).z); \
        a6 += lo_bf((U).w); a7 += hi_bf((U).w); } while (0)

    // ---- stage 0: edges [0, min(deg,32)), parity p owns e = 4j + p, j = 0..7 ----
    int d0 = (deg < 32) ? deg : 32;
    {
        int sA0 = __shfl(idx0, hb + p,      64);
        int sA1 = __shfl(idx0, hb + 4 + p,  64);
        int sA2 = __shfl(idx0, hb + 8 + p,  64);
        int sA3 = __shfl(idx0, hb + 12 + p, 64);
        uint4 uA0 = h128[sA0 * 8 + q];
        uint4 uA1 = h128[sA1 * 8 + q];
        uint4 uA2 = h128[sA2 * 8 + q];
        uint4 uA3 = h128[sA3 * 8 + q];
        int sB0 = __shfl(idx0, hb + 16 + p, 64);
        int sB1 = __shfl(idx0, hb + 20 + p, 64);
        int sB2 = __shfl(idx0, hb + 24 + p, 64);
        int sB3 = __shfl(idx0, hb + 28 + p, 64);
        uint4 uB0 = h128[sB0 * 8 + q];
        uint4 uB1 = h128[sB1 * 8 + q];
        uint4 uB2 = h128[sB2 * 8 + q];
        uint4 uB3 = h128[sB3 * 8 + q];
        if (p      < d0) ACC8(uA0);
        if (4 + p  < d0) ACC8(uA1);
        if (8 + p  < d0) ACC8(uA2);
        if (12 + p < d0) ACC8(uA3);
        if (16 + p < d0) ACC8(uB0);
        if (20 + p < d0) ACC8(uB1);
        if (24 + p < d0) ACC8(uB2);
        if (28 + p < d0) ACC8(uB3);
    }

    // ---- stage 1: edges [32, min(deg,64)) via idx1, local e' = e-32 in [0, m1) ----
    int m1 = ((deg < 64) ? deg : 64) - 32;
    if (m1 > 0) {
        int nj1 = (m1 + 3) >> 2;
        int j = 0;
        for (; 4 * j + 8 <= m1; j += 2) {
            int e0 = 4 * j + p;
            int s0 = __shfl(idx1, hb + e0,     64);
            int s1g = __shfl(idx1, hb + e0 + 4, 64);
            uint4 u0 = h128[s0 * 8 + q];
            uint4 u1 = h128[s1g * 8 + q];
            ACC8(u0);
            ACC8(u1);
        }
        for (; j < nj1; ++j) {
            int e = 4 * j + p;
            int s = __shfl(idx1, hb + e, 64);
            uint4 u = h128[s * 8 + q];
            if (e < m1) ACC8(u);
        }
    }

    // ---- rare tail: edges [64, deg), direct loads (no shfl -> divergence-safe) ----
    for (int e = 64 + p; e < deg; e += 4) {
        int s = esrc[beg + e];
        uint4 u = h128[s * 8 + q];
        ACC8(u);
    }
#undef ACC8

    // combine 4 parities (xor 8 flips p bit0, xor 16 flips p bit1; stays within half)
    a0 += __shfl_xor(a0, 8, 64);  a1 += __shfl_xor(a1, 8, 64);
    a2 += __shfl_xor(a2, 8, 64);  a3 += __shfl_xor(a3, 8, 64);
    a4 += __shfl_xor(a4, 8, 64);  a5 += __shfl_xor(a5, 8, 64);
    a6 += __shfl_xor(a6, 8, 64);  a7 += __shfl_xor(a7, 8, 64);
    a0 += __shfl_xor(a0, 16, 64); a1 += __shfl_xor(a1, 16, 64);
    a2 += __shfl_xor(a2, 16, 64); a3 += __shfl_xor(a3, 16, 64);
    a4 += __shfl_xor(a4, 16, 64); a5 += __shfl_xor(a5, 16, 64);
    a6 += __shfl_xor(a6, 16, 64); a7 += __shfl_xor(a7, 16, 64);

    float innorm = in_norm[node];
    float v0 = a0 * innorm, v1 = a1 * innorm, v2 = a2 * innorm, v3 = a3 * innorm;
    float v4 = a4 * innorm, v5 = a5 * innorm, v6 = a6 * innorm, v7 = a7 * innorm;

    if (mode == 0) {
        if (p == 0) {
            float on = out_norm[node];
            uint4 w;
            w.x = (uint32_t)f2bf(v0 * on) | ((uint32_t)f2bf(v1 * on) << 16);
            w.y = (uint32_t)f2bf(v2 * on) | ((uint32_t)f2bf(v3 * on) << 16);
            w.z = (uint32_t)f2bf(v4 * on) | ((uint32_t)f2bf(v5 * on) << 16);
            w.w = (uint32_t)f2bf(v6 * on) | ((uint32_t)f2bf(v7 * on) << 16);
            hn128[node * 8 + q] = w;
        }
    } else {
        // final: res = x + (h1_own*s1 + h2_own*s2)*rinv + e3*s3
        if (p == 1 || p == 2) {
            int of = node * 16 + 2 * q + (p - 1);
            float4 x = (node < USER_NUM) ? user4[of] : item4[of - USER_NUM * 16];
            uint2 h1 = h1own[of];
            uint2 h2 = ((const uint2*)h32)[of];   // gather table IS h2
            float rinv = 1.0f / out_norm[node];   // = sqrt(out_deg)
            float b0 = (p == 1) ? v0 : v4;
            float b1 = (p == 1) ? v1 : v5;
            float b2 = (p == 1) ? v2 : v6;
            float b3 = (p == 1) ? v3 : v7;
            float4 rv;
            rv.x = x.x + (lo_bf(h1.x) * s1 + lo_bf(h2.x) * s2) * rinv + b0 * s3;
            rv.y = x.y + (hi_bf(h1.x) * s1 + hi_bf(h2.x) * s2) * rinv + b1 * s3;
            rv.z = x.z + (lo_bf(h1.y) * s1 + lo_bf(h2.y) * s2) * rinv + b2 * s3;
            rv.w = x.w + (hi_bf(h1.y) * s1 + hi_bf(h2.y) * s2) * rinv + b3 * s3;
            res4[of] = rv;
        }
    }
}

static inline uintptr_t align_up(uintptr_t p, uintptr_t a) { return (p + a - 1) & ~(a - 1); }

extern "C" void kernel_launch(void* const* d_in, const int* in_sizes, int n_in,
                              void* d_out, int out_size, void* d_ws, size_t ws_size,
                              hipStream_t stream) {
    const float* user_emb = (const float*)d_in[0];
    const float* item_emb = (const float*)d_in[1];
    const int*   src      = (const int*)d_in[2];
    const int*   dst      = (const int*)d_in[3];
    float*       res      = (float*)d_out;

    // ---- workspace layout (~84 MB with lifetime aliasing) ----
    uintptr_t p = (uintptr_t)d_ws;
    int* in_cnt = (int*)p;                     p = align_up(p + (size_t)N_NODES * 4, 128);
    float* out_norm = (float*)p;               p = align_up(p + (size_t)N_NODES * 4, 128);
    float* in_norm = (float*)p;                p = align_up(p + (size_t)N_NODES * 4, 128);
    uint32_t* btot = (uint32_t*)p;             p = align_up(p + (size_t)(2 * NBUCK) * 4, 128);
    int* esrc = (int*)p;                       p = align_up(p + (size_t)NBUCK * BNODES * SLAB * 4, 128);
    uint32_t* hA = (uint32_t*)p;               p = align_up(p + (size_t)N_NODES * 32 * 4, 128); // 19.2MB
    uint32_t* hB = (uint32_t*)p;
    uint32_t* gcur = btot + NBUCK;             // zeroed together with btot
    // lifetime aliases:
    //   sorted (16MB) lives in hA        (overwritten by init's h0 after slab consumed it)
    //   out-deg partial (19.2MB) in hB   (overwritten by agg L0's h1; rednorm consumed it)
    uint32_t* sorted  = hA;
    uint32_t* partial = hB;

    const int BT = 256;
    int fb = (N_NODES * 32 + BT - 1) / BT;
    int ab = (N_NODES / 2 * 64 + BT - 1) / BT;   // 2 nodes per wave

    const float2* user2 = (const float2*)user_emb;
    const float2* item2 = (const float2*)item_emb;
    const float4* user4 = (const float4*)user_emb;
    const float4* item4 = (const float4*)item_emb;

    hipMemsetAsync(btot, 0, (size_t)(2 * NBUCK) * 4, stream);
    histfused_kernel<<<(HRANGES + 1) * SLICES, 512, 0, stream>>>(src, dst, partial, btot);
    rednorm_kernel<<<(HRANGES * RWORDS + 255) / 256, 256, 0, stream>>>(partial, out_norm);
    scatter_kernel<<<SSLICES, 512, 0, stream>>>(src, dst, btot, gcur, sorted);
    slab_kernel<<<NBUCK, 1024, 0, stream>>>(sorted, btot, esrc, in_cnt, in_norm);
    init_kernel<<<fb, BT, 0, stream>>>(user2, item2, out_norm, hA);

    // L0: gather h0(hA) -> pack h1(hB)
    agg_kernel<<<ab, BT, 0, stream>>>(hA, esrc, in_cnt, in_norm, out_norm, user4, item4,
                                      (float4*)res, (uint4*)hB, (const uint2*)hB,
                                      0.0f, 0.0f, 0.0f, 0);
    // L1: gather h1(hB) -> pack h2(hA)   (h0 dead)
    agg_kernel<<<ab, BT, 0, stream>>>(hB, esrc, in_cnt, in_norm, out_norm, user4, item4,
                                      (float4*)res, (uint4*)hA, (const uint2*)hB,
                                      0.0f, 0.0f, 0.0f, 0);
    // L2/final: gather h2(hA); res = x + (h1*1/2 + h2*1/3)*rinv + e3*1/4
    agg_kernel<<<ab, BT, 0, stream>>>(hA, esrc, in_cnt, in_norm, out_norm, user4, item4,
                                      (float4*)res, (uint4*)hB, (const uint2*)hB,
                                      0.5f, 1.0f / 3.0f, 0.25f, 1);
}

// Round 7
// 427.775 us; speedup vs baseline: 1.0072x; 1.0072x over previous
//
#include <hip/hip_runtime.h>
#include <stdint.h>

#define USER_NUM 100000
#define ITEM_NUM 50000
#define N_NODES  150000
#define HIDE_DIM 64
#define N_EDGES  4000000
#define SLAB     72   // max in-degree slab; prior rounds passed (no clipping at 72)

// ---- out-degree histogram (atomic-free, 8-bit packed LDS bins) ----
#define HRANGES 3
#define RNODES  50000
#define RWORDS  (RNODES / 4)
#define SLICES  128                    // 4M % 128 == 0 -> EPS exact
#define EPS     (N_EDGES / SLICES)     // 31250
#define NRB     ((HRANGES * RWORDS + 511) / 512)   // 74 rednorm blocks; block NRB = btot scan

// ---- bucket sort by dst ----
#define BSH     9
#define BNODES  512
#define NBUCK   293                    // ceil(150000/512)
#define SSLICES 640                    // LDS-staged scatter: slice = 6250 edges
#define EPSB    (N_EDGES / SSLICES)    // 6250, exact

// ---- slab staging ----
#define CHUNK   128                    // nodes per LDS staging chunk (128*72*4 = 36.8 KB)
#define NCHUNK  (BNODES / CHUNK)       // 4

// ---- bf16 helpers ----
__device__ __forceinline__ unsigned short f2bf(float f) {
    union { float f; unsigned int i; } c; c.f = f;
    unsigned int b = c.i;
    return (unsigned short)((b + 0x7FFFu + ((b >> 16) & 1u)) >> 16);
}
__device__ __forceinline__ float lo_bf(uint32_t u) {
    union { uint32_t u; float f; } c; c.u = u << 16; return c.f;
}
__device__ __forceinline__ float hi_bf(uint32_t u) {
    union { uint32_t u; float f; } c; c.u = u & 0xffff0000u; return c.f;
}

// ---------------- fused histograms ----------------
// blocks r in [0,3): out-degree partial hist of src for node range r (8-bit packed LDS bins)
// blocks r == 3   : dst bucket-total hist -> global atomicAdd into btot (37.5k atomics)
__global__ void histfused_kernel(const int* __restrict__ src, const int* __restrict__ dst,
                                 uint32_t* __restrict__ partial, uint32_t* __restrict__ btot) {
    __shared__ uint32_t bins[RWORDS];   // 50 KB; r==3 uses first NBUCK words
    int r  = blockIdx.x / SLICES;
    int sl = blockIdx.x - r * SLICES;
    int e0 = sl * EPS, e1 = e0 + EPS;   // exact slicing
    if (r < HRANGES) {
        for (int i = threadIdx.x; i < RWORDS; i += 512) bins[i] = 0;
        __syncthreads();
        int lo = r * RNODES, hi = lo + RNODES;
        for (int e = e0 + threadIdx.x; e < e1; e += 512) {
            int s = src[e];
            if (s >= lo && s < hi) {
                int x = s - lo;
                atomicAdd(&bins[x >> 2], 1u << (8 * (x & 3)));
            }
        }
        __syncthreads();
        uint32_t* out = partial + (size_t)(r * SLICES + sl) * RWORDS;
        for (int i = threadIdx.x; i < RWORDS; i += 512) out[i] = bins[i];
    } else {
        for (int i = threadIdx.x; i < NBUCK; i += 512) bins[i] = 0;
        __syncthreads();
        for (int e = e0 + threadIdx.x; e < e1; e += 512)
            atomicAdd(&bins[((unsigned)dst[e]) >> BSH], 1u);
        __syncthreads();
        for (int i = threadIdx.x; i < NBUCK; i += 512)
            if (bins[i]) atomicAdd(&btot[i], bins[i]);
    }
}

// ---------------- reduce out-degree partials -> out_norm; last block: scan btot -> bbase ----------
__global__ void rednorm_kernel(const uint32_t* __restrict__ partial, float* __restrict__ out_norm,
                               const uint32_t* __restrict__ btot, uint32_t* __restrict__ bbase) {
    if (blockIdx.x == NRB) {
        // exclusive scan of btot (293) -> bbase (done once here; scatter/slab just read it)
        __shared__ uint32_t tot[512];
        int t = threadIdx.x;
        uint32_t v = (t < NBUCK) ? btot[t] : 0;
        tot[t] = v;
        __syncthreads();
        for (int off = 1; off < 512; off <<= 1) {
            uint32_t x = (t >= off) ? tot[t - off] : 0;
            __syncthreads();
            tot[t] += x;
            __syncthreads();
        }
        if (t < NBUCK) bbase[t] = tot[t] - v;
        if (t == NBUCK - 1) bbase[NBUCK] = tot[t];
        return;
    }
    int g = blockIdx.x * 512 + threadIdx.x;
    if (g >= HRANGES * RWORDS) return;
    int r = g / RWORDS, w = g - r * RWORDS;
    const uint32_t* p = partial + (size_t)r * SLICES * RWORDS + w;
    uint32_t acc = 0;
#pragma unroll 16
    for (int sl = 0; sl < SLICES; ++sl) acc += p[(size_t)sl * RWORDS];
    int oc0 = acc & 255, oc1 = (acc >> 8) & 255, oc2 = (acc >> 16) & 255, oc3 = (acc >> 24);
    float4 o;
    o.x = 1.0f / sqrtf((float)(oc0 < 1 ? 1 : oc0));
    o.y = 1.0f / sqrtf((float)(oc1 < 1 ? 1 : oc1));
    o.z = 1.0f / sqrtf((float)(oc2 < 1 ? 1 : oc2));
    o.w = 1.0f / sqrtf((float)(oc3 < 1 ? 1 : oc3));
    ((float4*)out_norm)[(size_t)r * (RNODES / 4) + w] = o;
}

// ---------------- scatter v6: LDS-staged; bucket runs reserved via gcur (bbase precomputed) ------
__global__ void scatter_kernel(const int* __restrict__ src, const int* __restrict__ dst,
                               const uint32_t* __restrict__ bbase, uint32_t* __restrict__ gcur,
                               uint32_t* __restrict__ sorted) {
    __shared__ uint32_t cnt[NBUCK];    // counts -> then local cursor
    __shared__ uint32_t excl[NBUCK];   // local exclusive scan
    __shared__ uint32_t gpos0[NBUCK];  // reserved global run start per bucket
    __shared__ uint32_t sarr[512];     // scan workspace
    __shared__ uint32_t sval[EPSB];    // staged packed values, bucket-grouped (25 KB)
    __shared__ uint16_t sbkt[EPSB];    // bucket id per staged entry (12.5 KB)

    int s = blockIdx.x;
    int t = threadIdx.x;
    for (int i = t; i < NBUCK; i += 512) cnt[i] = 0;
    __syncthreads();

    int e0 = s * EPSB;
    // pass 1: count
    for (int e = e0 + t; e < e0 + EPSB; e += 512)
        atomicAdd(&cnt[((unsigned)dst[e]) >> BSH], 1u);
    __syncthreads();

    // local inclusive scan over 293 counts (Hillis-Steele on 512 slots)
    uint32_t myc = (t < NBUCK) ? cnt[t] : 0;
    sarr[t] = myc;
    __syncthreads();
    for (int off = 1; off < 512; off <<= 1) {
        uint32_t x = (t >= off) ? sarr[t - off] : 0;
        __syncthreads();
        sarr[t] += x;
        __syncthreads();
    }
    if (t < NBUCK) {
        uint32_t ex = sarr[t] - myc;
        excl[t] = ex;
        cnt[t] = ex;                                              // local cursor starts at excl
        if (myc) gpos0[t] = bbase[t] + atomicAdd(&gcur[t], myc);  // reserve contiguous run
    }
    __syncthreads();

    // pass 2: place into LDS grouped by bucket, tag with bucket id
    for (int e = e0 + t; e < e0 + EPSB; e += 512) {
        unsigned d = (unsigned)dst[e];
        int sv = src[e];
        unsigned b = d >> BSH;
        unsigned nib = d & (BNODES - 1);
        uint32_t r = atomicAdd(&cnt[b], 1u);
        sval[r] = (uint32_t)sv | (nib << 18);
        sbkt[r] = (uint16_t)b;
    }
    __syncthreads();

    // pass 3: stream out (coalesced within bucket runs)
    for (int i = t; i < EPSB; i += 512) {
        unsigned b = sbkt[i];
        sorted[gpos0[b] + ((uint32_t)i - excl[b])] = sval[i];
    }
}

// ---------------- slab v2: LDS-staged esrc image -> fully coalesced streaming writes -----------
// Per bucket: count pass (in_cnt/in_norm), then 4 chunk passes; each places 128 nodes'
// edges into a 36.8 KB LDS slab image and streams it out in full lines. Eliminates the
// scattered-4B-store partial-line writebacks of v1. Edge re-reads are L2-hot (~54 KB).
__global__ __launch_bounds__(1024) void slab_kernel(
        const uint32_t* __restrict__ sorted, const uint32_t* __restrict__ btot,
        const uint32_t* __restrict__ bbase,
        int* __restrict__ esrc, int* __restrict__ in_cnt, float* __restrict__ in_norm) {
    __shared__ uint32_t cur[BNODES];
    __shared__ uint32_t cur2[CHUNK];
    __shared__ int stage[CHUNK * SLAB];   // 36.8 KB
    int b = blockIdx.x;
    int t = threadIdx.x;
    if (t < BNODES) cur[t] = 0;
    __syncthreads();
    uint32_t start = bbase[b];
    uint32_t n = btot[b];

    // pass 0: per-node counts -> in_cnt / in_norm
    for (uint32_t i = t; i < n; i += 1024)
        atomicAdd(&cur[sorted[start + i] >> 18], 1u);
    __syncthreads();
    if (t < BNODES) {
        int node = (b << BSH) + t;
        if (node < N_NODES) {
            int ic = (int)cur[t];
            in_cnt[node] = ic;
            in_norm[node] = 1.0f / sqrtf((float)(ic < 1 ? 1 : ic));
        }
    }

    // chunk passes: stage 128 nodes' slab rows in LDS, stream out coalesced
    for (int c = 0; c < NCHUNK; ++c) {
        if (t < CHUNK) cur2[t] = 0;
        __syncthreads();                      // also orders prev stream-out before placements
        int lo = c * CHUNK, hi = lo + CHUNK;
        for (uint32_t i = t; i < n; i += 1024) {
            uint32_t v = sorted[start + i];
            int nib = (int)(v >> 18);
            if (nib >= lo && nib < hi) {
                uint32_t r = atomicAdd(&cur2[nib - lo], 1u);
                if (r < SLAB) stage[(nib - lo) * SLAB + r] = (int)(v & 0x3FFFFu);
            }
        }
        __syncthreads();
        int* dp = esrc + ((size_t)(b << BSH) + lo) * SLAB;
        for (int i = t; i < CHUNK * SLAB; i += 1024) dp[i] = stage[i];
        // (unused slots carry stale LDS data; agg never reads beyond deg)
    }
}

// ---------------- init: h0 = bf16(x * out_norm), packed u32 ----------------
__global__ void init_kernel(const float2* __restrict__ user2, const float2* __restrict__ item2,
                            const float* __restrict__ out_norm, uint32_t* __restrict__ h0) {
    int gid = blockIdx.x * blockDim.x + threadIdx.x;
    if (gid >= N_NODES * 32) return;
    int node = gid >> 5;
    float2 v = (node < USER_NUM) ? user2[gid] : item2[gid - USER_NUM * 32];
    float on = out_norm[node];
    h0[gid] = (uint32_t)f2bf(v.x * on) | ((uint32_t)f2bf(v.y * on) << 16);
}

// ---------------- gather aggregation v9 (core FROZEN at L2/L3 request-rate ceiling) ----------------
// lane = (half = node [bit5], p = edge parity [bits3-4], q = 16B col [bits0-2]).
// mode 0 (L0, L1): hn = pack(emb*on)                       [pure pack, no res traffic]
// mode 1 (L2/final): res = x + (h1_own*s1 + h2_own*s2)*rinv + e3*s3
__global__ void agg_kernel(const uint32_t* __restrict__ h32, const int* __restrict__ esrc,
                           const int* __restrict__ in_cnt,
                           const float* __restrict__ in_norm, const float* __restrict__ out_norm,
                           const float4* __restrict__ user4, const float4* __restrict__ item4,
                           float4* __restrict__ res4, uint4* __restrict__ hn128,
                           const uint2* __restrict__ h1own,
                           float s1, float s2, float s3, int mode) {
    int wid  = (blockIdx.x * blockDim.x + threadIdx.x) >> 6;
    int lane = threadIdx.x & 63;
    int half = lane >> 5;
    int p    = (lane >> 3) & 3;
    int q    = lane & 7;
    int node = wid * 2 + half;
    if (node >= N_NODES) return;

    int deg = in_cnt[node]; if (deg > SLAB) deg = SLAB;
    int beg = node * SLAB;
    int hb  = half << 5;

    // half-lane l holds edge l in idx0 and edge 32+l in idx1 (masked to 0 if OOR)
    int sl0 = lane & 31;
    int idx0 = (sl0      < deg) ? esrc[beg + sl0]      : 0;
    int idx1 = (sl0 + 32 < deg) ? esrc[beg + sl0 + 32] : 0;

    const uint4* h128 = (const uint4*)h32;   // 8 x uint4 per node (128B)

    float a0 = 0.f, a1 = 0.f, a2 = 0.f, a3 = 0.f;
    float a4 = 0.f, a5 = 0.f, a6 = 0.f, a7 = 0.f;

#define ACC8(U) do { \
        a0 += lo_bf((U).x); a1 += hi_bf((U).x); \
        a2 += lo_bf((U).y); a3 += hi_bf((U).y); \
        a4 += lo_bf((U).z); a5 += hi_bf((U).z); \
        a6 += lo_bf((U).w); a7 += hi_bf((U).w); } while (0)

    // ---- stage 0: edges [0, min(deg,32)), parity p owns e = 4j + p, j = 0..7 ----
    int d0 = (deg < 32) ? deg : 32;
    {
        int sA0 = __shfl(idx0, hb + p,      64);
        int sA1 = __shfl(idx0, hb + 4 + p,  64);
        int sA2 = __shfl(idx0, hb + 8 + p,  64);
        int sA3 = __shfl(idx0, hb + 12 + p, 64);
        uint4 uA0 = h128[sA0 * 8 + q];
        uint4 uA1 = h128[sA1 * 8 + q];
        uint4 uA2 = h128[sA2 * 8 + q];
        uint4 uA3 = h128[sA3 * 8 + q];
        int sB0 = __shfl(idx0, hb + 16 + p, 64);
        int sB1 = __shfl(idx0, hb + 20 + p, 64);
        int sB2 = __shfl(idx0, hb + 24 + p, 64);
        int sB3 = __shfl(idx0, hb + 28 + p, 64);
        uint4 uB0 = h128[sB0 * 8 + q];
        uint4 uB1 = h128[sB1 * 8 + q];
        uint4 uB2 = h128[sB2 * 8 + q];
        uint4 uB3 = h128[sB3 * 8 + q];
        if (p      < d0) ACC8(uA0);
        if (4 + p  < d0) ACC8(uA1);
        if (8 + p  < d0) ACC8(uA2);
        if (12 + p < d0) ACC8(uA3);
        if (16 + p < d0) ACC8(uB0);
        if (20 + p < d0) ACC8(uB1);
        if (24 + p < d0) ACC8(uB2);
        if (28 + p < d0) ACC8(uB3);
    }

    // ---- stage 1: edges [32, min(deg,64)) via idx1, local e' = e-32 in [0, m1) ----
    int m1 = ((deg < 64) ? deg : 64) - 32;
    if (m1 > 0) {
        int nj1 = (m1 + 3) >> 2;
        int j = 0;
        for (; 4 * j + 8 <= m1; j += 2) {
            int e0 = 4 * j + p;
            int s0 = __shfl(idx1, hb + e0,     64);
            int s1g = __shfl(idx1, hb + e0 + 4, 64);
            uint4 u0 = h128[s0 * 8 + q];
            uint4 u1 = h128[s1g * 8 + q];
            ACC8(u0);
            ACC8(u1);
        }
        for (; j < nj1; ++j) {
            int e = 4 * j + p;
            int s = __shfl(idx1, hb + e, 64);
            uint4 u = h128[s * 8 + q];
            if (e < m1) ACC8(u);
        }
    }

    // ---- rare tail: edges [64, deg), direct loads (no shfl -> divergence-safe) ----
    for (int e = 64 + p; e < deg; e += 4) {
        int s = esrc[beg + e];
        uint4 u = h128[s * 8 + q];
        ACC8(u);
    }
#undef ACC8

    // combine 4 parities (xor 8 flips p bit0, xor 16 flips p bit1; stays within half)
    a0 += __shfl_xor(a0, 8, 64);  a1 += __shfl_xor(a1, 8, 64);
    a2 += __shfl_xor(a2, 8, 64);  a3 += __shfl_xor(a3, 8, 64);
    a4 += __shfl_xor(a4, 8, 64);  a5 += __shfl_xor(a5, 8, 64);
    a6 += __shfl_xor(a6, 8, 64);  a7 += __shfl_xor(a7, 8, 64);
    a0 += __shfl_xor(a0, 16, 64); a1 += __shfl_xor(a1, 16, 64);
    a2 += __shfl_xor(a2, 16, 64); a3 += __shfl_xor(a3, 16, 64);
    a4 += __shfl_xor(a4, 16, 64); a5 += __shfl_xor(a5, 16, 64);
    a6 += __shfl_xor(a6, 16, 64); a7 += __shfl_xor(a7, 16, 64);

    float innorm = in_norm[node];
    float v0 = a0 * innorm, v1 = a1 * innorm, v2 = a2 * innorm, v3 = a3 * innorm;
    float v4 = a4 * innorm, v5 = a5 * innorm, v6 = a6 * innorm, v7 = a7 * innorm;

    if (mode == 0) {
        if (p == 0) {
            float on = out_norm[node];
            uint4 w;
            w.x = (uint32_t)f2bf(v0 * on) | ((uint32_t)f2bf(v1 * on) << 16);
            w.y = (uint32_t)f2bf(v2 * on) | ((uint32_t)f2bf(v3 * on) << 16);
            w.z = (uint32_t)f2bf(v4 * on) | ((uint32_t)f2bf(v5 * on) << 16);
            w.w = (uint32_t)f2bf(v6 * on) | ((uint32_t)f2bf(v7 * on) << 16);
            hn128[node * 8 + q] = w;
        }
    } else {
        // final: res = x + (h1_own*s1 + h2_own*s2)*rinv + e3*s3
        if (p == 1 || p == 2) {
            int of = node * 16 + 2 * q + (p - 1);
            float4 x = (node < USER_NUM) ? user4[of] : item4[of - USER_NUM * 16];
            uint2 h1 = h1own[of];
            uint2 h2 = ((const uint2*)h32)[of];   // gather table IS h2
            float rinv = 1.0f / out_norm[node];   // = sqrt(out_deg)
            float b0 = (p == 1) ? v0 : v4;
            float b1 = (p == 1) ? v1 : v5;
            float b2 = (p == 1) ? v2 : v6;
            float b3 = (p == 1) ? v3 : v7;
            float4 rv;
            rv.x = x.x + (lo_bf(h1.x) * s1 + lo_bf(h2.x) * s2) * rinv + b0 * s3;
            rv.y = x.y + (hi_bf(h1.x) * s1 + hi_bf(h2.x) * s2) * rinv + b1 * s3;
            rv.z = x.z + (lo_bf(h1.y) * s1 + lo_bf(h2.y) * s2) * rinv + b2 * s3;
            rv.w = x.w + (hi_bf(h1.y) * s1 + hi_bf(h2.y) * s2) * rinv + b3 * s3;
            res4[of] = rv;
        }
    }
}

static inline uintptr_t align_up(uintptr_t p, uintptr_t a) { return (p + a - 1) & ~(a - 1); }

extern "C" void kernel_launch(void* const* d_in, const int* in_sizes, int n_in,
                              void* d_out, int out_size, void* d_ws, size_t ws_size,
                              hipStream_t stream) {
    const float* user_emb = (const float*)d_in[0];
    const float* item_emb = (const float*)d_in[1];
    const int*   src      = (const int*)d_in[2];
    const int*   dst      = (const int*)d_in[3];
    float*       res      = (float*)d_out;

    // ---- workspace layout (~84 MB with lifetime aliasing) ----
    uintptr_t p = (uintptr_t)d_ws;
    int* in_cnt = (int*)p;                     p = align_up(p + (size_t)N_NODES * 4, 128);
    float* out_norm = (float*)p;               p = align_up(p + (size_t)N_NODES * 4, 128);
    float* in_norm = (float*)p;                p = align_up(p + (size_t)N_NODES * 4, 128);
    uint32_t* btot = (uint32_t*)p;             p = align_up(p + (size_t)(2 * NBUCK) * 4, 128);
    uint32_t* bbase = (uint32_t*)p;            p = align_up(p + (size_t)(NBUCK + 1) * 4, 128);
    int* esrc = (int*)p;                       p = align_up(p + (size_t)NBUCK * BNODES * SLAB * 4, 128);
    uint32_t* hA = (uint32_t*)p;               p = align_up(p + (size_t)N_NODES * 32 * 4, 128); // 19.2MB
    uint32_t* hB = (uint32_t*)p;
    uint32_t* gcur = btot + NBUCK;             // zeroed together with btot
    // lifetime aliases:
    //   sorted (16MB) lives in hA        (overwritten by init's h0 after slab consumed it)
    //   out-deg partial (19.2MB) in hB   (overwritten by agg L0's h1; rednorm consumed it)
    uint32_t* sorted  = hA;
    uint32_t* partial = hB;

    const int BT = 256;
    int fb = (N_NODES * 32 + BT - 1) / BT;
    int ab = (N_NODES / 2 * 64 + BT - 1) / BT;   // 2 nodes per wave

    const float2* user2 = (const float2*)user_emb;
    const float2* item2 = (const float2*)item_emb;
    const float4* user4 = (const float4*)user_emb;
    const float4* item4 = (const float4*)item_emb;

    hipMemsetAsync(btot, 0, (size_t)(2 * NBUCK) * 4, stream);
    histfused_kernel<<<(HRANGES + 1) * SLICES, 512, 0, stream>>>(src, dst, partial, btot);
    rednorm_kernel<<<NRB + 1, 512, 0, stream>>>(partial, out_norm, btot, bbase);
    scatter_kernel<<<SSLICES, 512, 0, stream>>>(src, dst, bbase, gcur, sorted);
    slab_kernel<<<NBUCK, 1024, 0, stream>>>(sorted, btot, bbase, esrc, in_cnt, in_norm);
    init_kernel<<<fb, BT, 0, stream>>>(user2, item2, out_norm, hA);

    // L0: gather h0(hA) -> pack h1(hB)
    agg_kernel<<<ab, BT, 0, stream>>>(hA, esrc, in_cnt, in_norm, out_norm, user4, item4,
                                      (float4*)res, (uint4*)hB, (const uint2*)hB,
                                      0.0f, 0.0f, 0.0f, 0);
    // L1: gather h1(hB) -> pack h2(hA)   (h0 dead)
    agg_kernel<<<ab, BT, 0, stream>>>(hB, esrc, in_cnt, in_norm, out_norm, user4, item4,
                                      (float4*)res, (uint4*)hA, (const uint2*)hB,
                                      0.0f, 0.0f, 0.0f, 0);
    // L2/final: gather h2(hA); res = x + (h1*1/2 + h2*1/3)*rinv + e3*1/4
    agg_kernel<<<ab, BT, 0, stream>>>(hA, esrc, in_cnt, in_norm, out_norm, user4, item4,
                                      (float4*)res, (uint4*)hB, (const uint2*)hB,
                                      0.5f, 1.0f / 3.0f, 0.25f, 1);
}

// Round 8
// 412.900 us; speedup vs baseline: 1.0435x; 1.0360x over previous
//
#include <hip/hip_runtime.h>
#include <stdint.h>

#define USER_NUM 100000
#define ITEM_NUM 50000
#define N_NODES  150000
#define HIDE_DIM 64
#define N_EDGES  4000000

// ---- out-degree histogram (atomic-free, 8-bit packed LDS bins) ----
#define HRANGES 3
#define RNODES  50000
#define RWORDS  (RNODES / 4)
#define SLICES  128                    // 4M % 128 == 0 -> EPS exact
#define EPS     (N_EDGES / SLICES)     // 31250
#define NRB     ((HRANGES * RWORDS + 511) / 512)   // 74 rednorm blocks; block NRB = btot scan

// ---- bucket sort by dst ----
#define BSH     9
#define BNODES  512
#define NBUCK   293                    // ceil(150000/512)
#define SSLICES 640                    // LDS-staged scatter: slice = 6250 edges
#define EPSB    (N_EDGES / SSLICES)    // 6250, exact

// ---- slab CSR staging ----
#define STAGE_CAP 15000                // max bucket edges staged in LDS (binomial max ~14.1k)
#define INIT_BLOCKS ((N_NODES * 32) / 512)   // 9375, exact

// ---- bf16 helpers ----
__device__ __forceinline__ unsigned short f2bf(float f) {
    union { float f; unsigned int i; } c; c.f = f;
    unsigned int b = c.i;
    return (unsigned short)((b + 0x7FFFu + ((b >> 16) & 1u)) >> 16);
}
__device__ __forceinline__ float lo_bf(uint32_t u) {
    union { uint32_t u; float f; } c; c.u = u << 16; return c.f;
}
__device__ __forceinline__ float hi_bf(uint32_t u) {
    union { uint32_t u; float f; } c; c.u = u & 0xffff0000u; return c.f;
}

// ---------------- fused histograms ----------------
// blocks r in [0,3): out-degree partial hist of src for node range r (8-bit packed LDS bins)
// blocks r == 3   : dst bucket-total hist -> global atomicAdd into btot (37.5k atomics)
__global__ void histfused_kernel(const int* __restrict__ src, const int* __restrict__ dst,
                                 uint32_t* __restrict__ partial, uint32_t* __restrict__ btot) {
    __shared__ uint32_t bins[RWORDS];   // 50 KB; r==3 uses first NBUCK words
    int r  = blockIdx.x / SLICES;
    int sl = blockIdx.x - r * SLICES;
    int e0 = sl * EPS, e1 = e0 + EPS;   // exact slicing
    if (r < HRANGES) {
        for (int i = threadIdx.x; i < RWORDS; i += 512) bins[i] = 0;
        __syncthreads();
        int lo = r * RNODES, hi = lo + RNODES;
        for (int e = e0 + threadIdx.x; e < e1; e += 512) {
            int s = src[e];
            if (s >= lo && s < hi) {
                int x = s - lo;
                atomicAdd(&bins[x >> 2], 1u << (8 * (x & 3)));
            }
        }
        __syncthreads();
        uint32_t* out = partial + (size_t)(r * SLICES + sl) * RWORDS;
        for (int i = threadIdx.x; i < RWORDS; i += 512) out[i] = bins[i];
    } else {
        for (int i = threadIdx.x; i < NBUCK; i += 512) bins[i] = 0;
        __syncthreads();
        for (int e = e0 + threadIdx.x; e < e1; e += 512)
            atomicAdd(&bins[((unsigned)dst[e]) >> BSH], 1u);
        __syncthreads();
        for (int i = threadIdx.x; i < NBUCK; i += 512)
            if (bins[i]) atomicAdd(&btot[i], bins[i]);
    }
}

// ---------------- reduce out-degree partials -> out_norm; last block: scan btot -> bbase ----------
__global__ void rednorm_kernel(const uint32_t* __restrict__ partial, float* __restrict__ out_norm,
                               const uint32_t* __restrict__ btot, uint32_t* __restrict__ bbase) {
    if (blockIdx.x == NRB) {
        __shared__ uint32_t tot[512];
        int t = threadIdx.x;
        uint32_t v = (t < NBUCK) ? btot[t] : 0;
        tot[t] = v;
        __syncthreads();
        for (int off = 1; off < 512; off <<= 1) {
            uint32_t x = (t >= off) ? tot[t - off] : 0;
            __syncthreads();
            tot[t] += x;
            __syncthreads();
        }
        if (t < NBUCK) bbase[t] = tot[t] - v;
        if (t == NBUCK - 1) bbase[NBUCK] = tot[t];
        return;
    }
    int g = blockIdx.x * 512 + threadIdx.x;
    if (g >= HRANGES * RWORDS) return;
    int r = g / RWORDS, w = g - r * RWORDS;
    const uint32_t* p = partial + (size_t)r * SLICES * RWORDS + w;
    uint32_t acc = 0;
#pragma unroll 16
    for (int sl = 0; sl < SLICES; ++sl) acc += p[(size_t)sl * RWORDS];
    int oc0 = acc & 255, oc1 = (acc >> 8) & 255, oc2 = (acc >> 16) & 255, oc3 = (acc >> 24);
    float4 o;
    o.x = 1.0f / sqrtf((float)(oc0 < 1 ? 1 : oc0));
    o.y = 1.0f / sqrtf((float)(oc1 < 1 ? 1 : oc1));
    o.z = 1.0f / sqrtf((float)(oc2 < 1 ? 1 : oc2));
    o.w = 1.0f / sqrtf((float)(oc3 < 1 ? 1 : oc3));
    ((float4*)out_norm)[(size_t)r * (RNODES / 4) + w] = o;
}

// ---------------- scatter v6: LDS-staged; bucket runs reserved via gcur (bbase precomputed) ------
__global__ void scatter_kernel(const int* __restrict__ src, const int* __restrict__ dst,
                               const uint32_t* __restrict__ bbase, uint32_t* __restrict__ gcur,
                               uint32_t* __restrict__ sorted) {
    __shared__ uint32_t cnt[NBUCK];    // counts -> then local cursor
    __shared__ uint32_t excl[NBUCK];   // local exclusive scan
    __shared__ uint32_t gpos0[NBUCK];  // reserved global run start per bucket
    __shared__ uint32_t sarr[512];     // scan workspace
    __shared__ uint32_t sval[EPSB];    // staged packed values, bucket-grouped (25 KB)
    __shared__ uint16_t sbkt[EPSB];    // bucket id per staged entry (12.5 KB)

    int s = blockIdx.x;
    int t = threadIdx.x;
    for (int i = t; i < NBUCK; i += 512) cnt[i] = 0;
    __syncthreads();

    int e0 = s * EPSB;
    // pass 1: count
    for (int e = e0 + t; e < e0 + EPSB; e += 512)
        atomicAdd(&cnt[((unsigned)dst[e]) >> BSH], 1u);
    __syncthreads();

    // local inclusive scan over 293 counts (Hillis-Steele on 512 slots)
    uint32_t myc = (t < NBUCK) ? cnt[t] : 0;
    sarr[t] = myc;
    __syncthreads();
    for (int off = 1; off < 512; off <<= 1) {
        uint32_t x = (t >= off) ? sarr[t - off] : 0;
        __syncthreads();
        sarr[t] += x;
        __syncthreads();
    }
    if (t < NBUCK) {
        uint32_t ex = sarr[t] - myc;
        excl[t] = ex;
        cnt[t] = ex;                                              // local cursor starts at excl
        if (myc) gpos0[t] = bbase[t] + atomicAdd(&gcur[t], myc);  // reserve contiguous run
    }
    __syncthreads();

    // pass 2: place into LDS grouped by bucket, tag with bucket id
    for (int e = e0 + t; e < e0 + EPSB; e += 512) {
        unsigned d = (unsigned)dst[e];
        int sv = src[e];
        unsigned b = d >> BSH;
        unsigned nib = d & (BNODES - 1);
        uint32_t r = atomicAdd(&cnt[b], 1u);
        sval[r] = (uint32_t)sv | (nib << 18);
        sbkt[r] = (uint16_t)b;
    }
    __syncthreads();

    // pass 3: stream out (coalesced within bucket runs)
    for (int i = t; i < EPSB; i += 512) {
        unsigned b = sbkt[i];
        sorted[gpos0[b] + ((uint32_t)i - excl[b])] = sval[i];
    }
}

// ---------------- slab v3 + init fused ----------------
// blocks [0, NBUCK): CSR slab build. Per bucket: count pass -> in_cnt/in_norm + local
//   prefix -> rowptr (= bbase[b] + excl); pass 2 builds the COMPACT bucket image in LDS
//   (<= 60 KB) and streams it out fully coalesced. 2 reads of sorted (was 5), 16 MB
//   written (was 43.2 MB padded). Fallback to scattered stores if bucket > STAGE_CAP.
// blocks [NBUCK, NBUCK+INIT_BLOCKS): init h0 = bf16(x * out_norm) -> hB (partial is dead;
//   h0 CANNOT live in hA because slab blocks of this same kernel still read sorted there).
__global__ __launch_bounds__(512) void slabinit_kernel(
        const uint32_t* __restrict__ sorted, const uint32_t* __restrict__ btot,
        const uint32_t* __restrict__ bbase,
        int* __restrict__ esrc, int* __restrict__ in_cnt, float* __restrict__ in_norm,
        uint32_t* __restrict__ rowptr,
        const float2* __restrict__ user2, const float2* __restrict__ item2,
        const float* __restrict__ out_norm, uint32_t* __restrict__ h0) {
    int t = threadIdx.x;
    if (blockIdx.x >= NBUCK) {
        int gid = (blockIdx.x - NBUCK) * 512 + t;
        if (gid < N_NODES * 32) {
            int node = gid >> 5;
            float2 v = (node < USER_NUM) ? user2[gid] : item2[gid - USER_NUM * 32];
            float on = out_norm[node];
            h0[gid] = (uint32_t)f2bf(v.x * on) | ((uint32_t)f2bf(v.y * on) << 16);
        }
        return;
    }
    __shared__ uint32_t cnt[BNODES];
    __shared__ uint32_t sarr[BNODES];
    __shared__ int stage[STAGE_CAP];    // 60 KB
    int b = blockIdx.x;
    uint32_t start = bbase[b];
    uint32_t n = btot[b];
    cnt[t] = 0;
    __syncthreads();

    // pass 0: per-node counts
    for (uint32_t i = t; i < n; i += 512)
        atomicAdd(&cnt[sorted[start + i] >> 18], 1u);
    __syncthreads();

    // scan 512 node counts -> local exclusive prefix
    uint32_t v = cnt[t];
    sarr[t] = v;
    __syncthreads();
    for (int off = 1; off < 512; off <<= 1) {
        uint32_t x = (t >= off) ? sarr[t - off] : 0;
        __syncthreads();
        sarr[t] += x;
        __syncthreads();
    }
    uint32_t excl = sarr[t] - v;
    int node = (b << BSH) + t;
    if (node < N_NODES) {
        rowptr[node] = start + excl;
        in_cnt[node] = (int)v;
        in_norm[node] = 1.0f / sqrtf((float)(v < 1 ? 1 : v));
    }
    cnt[t] = excl;          // cursor starts at local exclusive offset
    __syncthreads();

    if (n <= STAGE_CAP) {
        // pass 2: build compact image in LDS, stream out coalesced
        for (uint32_t i = t; i < n; i += 512) {
            uint32_t w = sorted[start + i];
            uint32_t r = atomicAdd(&cnt[w >> 18], 1u);
            stage[r] = (int)(w & 0x3FFFFu);
        }
        __syncthreads();
        for (uint32_t i = t; i < n; i += 512) esrc[start + i] = stage[i];
    } else {
        // fallback (statistically unreachable): scattered but correct
        for (uint32_t i = t; i < n; i += 512) {
            uint32_t w = sorted[start + i];
            uint32_t r = atomicAdd(&cnt[w >> 18], 1u);
            esrc[start + r] = (int)(w & 0x3FFFFu);
        }
    }
}

// ---------------- gather aggregation v10: core FROZEN; CSR addressing ----------------
// lane = (half = node [bit5], p = edge parity [bits3-4], q = 16B col [bits0-2]).
// mode 0 (L0, L1): hn = pack(emb*on)                       [pure pack, no res traffic]
// mode 1 (L2/final): res = x + (h1_own*s1 + h2_own*s2)*rinv + e3*s3
__global__ void agg_kernel(const uint32_t* __restrict__ h32, const int* __restrict__ esrc,
                           const uint32_t* __restrict__ rowptr, const int* __restrict__ in_cnt,
                           const float* __restrict__ in_norm, const float* __restrict__ out_norm,
                           const float4* __restrict__ user4, const float4* __restrict__ item4,
                           float4* __restrict__ res4, uint4* __restrict__ hn128,
                           const uint2* __restrict__ h1own,
                           float s1, float s2, float s3, int mode) {
    int wid  = (blockIdx.x * blockDim.x + threadIdx.x) >> 6;
    int lane = threadIdx.x & 63;
    int half = lane >> 5;
    int p    = (lane >> 3) & 3;
    int q    = lane & 7;
    int node = wid * 2 + half;
    if (node >= N_NODES) return;

    int deg = in_cnt[node];
    int beg = (int)rowptr[node];          // CSR: exact, no clipping
    int hb  = half << 5;

    // half-lane l holds edge l in idx0 and edge 32+l in idx1 (masked to 0 if OOR)
    int sl0 = lane & 31;
    int idx0 = (sl0      < deg) ? esrc[beg + sl0]      : 0;
    int idx1 = (sl0 + 32 < deg) ? esrc[beg + sl0 + 32] : 0;

    const uint4* h128 = (const uint4*)h32;   // 8 x uint4 per node (128B)

    float a0 = 0.f, a1 = 0.f, a2 = 0.f, a3 = 0.f;
    float a4 = 0.f, a5 = 0.f, a6 = 0.f, a7 = 0.f;

#define ACC8(U) do { \
        a0 += lo_bf((U).x); a1 += hi_bf((U).x); \
        a2 += lo_bf((U).y); a3 += hi_bf((U).y); \
        a4 += lo_bf((U).z); a5 += hi_bf((U).z); \
        a6 += lo_bf((U).w); a7 += hi_bf((U).w); } while (0)

    // ---- stage 0: edges [0, min(deg,32)), parity p owns e = 4j + p, j = 0..7 ----
    int d0 = (deg < 32) ? deg : 32;
    {
        int sA0 = __shfl(idx0, hb + p,      64);
        int sA1 = __shfl(idx0, hb + 4 + p,  64);
        int sA2 = __shfl(idx0, hb + 8 + p,  64);
        int sA3 = __shfl(idx0, hb + 12 + p, 64);
        uint4 uA0 = h128[sA0 * 8 + q];
        uint4 uA1 = h128[sA1 * 8 + q];
        uint4 uA2 = h128[sA2 * 8 + q];
        uint4 uA3 = h128[sA3 * 8 + q];
        int sB0 = __shfl(idx0, hb + 16 + p, 64);
        int sB1 = __shfl(idx0, hb + 20 + p, 64);
        int sB2 = __shfl(idx0, hb + 24 + p, 64);
        int sB3 = __shfl(idx0, hb + 28 + p, 64);
        uint4 uB0 = h128[sB0 * 8 + q];
        uint4 uB1 = h128[sB1 * 8 + q];
        uint4 uB2 = h128[sB2 * 8 + q];
        uint4 uB3 = h128[sB3 * 8 + q];
        if (p      < d0) ACC8(uA0);
        if (4 + p  < d0) ACC8(uA1);
        if (8 + p  < d0) ACC8(uA2);
        if (12 + p < d0) ACC8(uA3);
        if (16 + p < d0) ACC8(uB0);
        if (20 + p < d0) ACC8(uB1);
        if (24 + p < d0) ACC8(uB2);
        if (28 + p < d0) ACC8(uB3);
    }

    // ---- stage 1: edges [32, min(deg,64)) via idx1, local e' = e-32 in [0, m1) ----
    int m1 = ((deg < 64) ? deg : 64) - 32;
    if (m1 > 0) {
        int nj1 = (m1 + 3) >> 2;
        int j = 0;
        for (; 4 * j + 8 <= m1; j += 2) {
            int e0 = 4 * j + p;
            int s0 = __shfl(idx1, hb + e0,     64);
            int s1g = __shfl(idx1, hb + e0 + 4, 64);
            uint4 u0 = h128[s0 * 8 + q];
            uint4 u1 = h128[s1g * 8 + q];
            ACC8(u0);
            ACC8(u1);
        }
        for (; j < nj1; ++j) {
            int e = 4 * j + p;
            int s = __shfl(idx1, hb + e, 64);
            uint4 u = h128[s * 8 + q];
            if (e < m1) ACC8(u);
        }
    }

    // ---- rare tail: edges [64, deg), direct loads (no shfl -> divergence-safe) ----
    for (int e = 64 + p; e < deg; e += 4) {
        int s = esrc[beg + e];
        uint4 u = h128[s * 8 + q];
        ACC8(u);
    }
#undef ACC8

    // combine 4 parities (xor 8 flips p bit0, xor 16 flips p bit1; stays within half)
    a0 += __shfl_xor(a0, 8, 64);  a1 += __shfl_xor(a1, 8, 64);
    a2 += __shfl_xor(a2, 8, 64);  a3 += __shfl_xor(a3, 8, 64);
    a4 += __shfl_xor(a4, 8, 64);  a5 += __shfl_xor(a5, 8, 64);
    a6 += __shfl_xor(a6, 8, 64);  a7 += __shfl_xor(a7, 8, 64);
    a0 += __shfl_xor(a0, 16, 64); a1 += __shfl_xor(a1, 16, 64);
    a2 += __shfl_xor(a2, 16, 64); a3 += __shfl_xor(a3, 16, 64);
    a4 += __shfl_xor(a4, 16, 64); a5 += __shfl_xor(a5, 16, 64);
    a6 += __shfl_xor(a6, 16, 64); a7 += __shfl_xor(a7, 16, 64);

    float innorm = in_norm[node];
    float v0 = a0 * innorm, v1 = a1 * innorm, v2 = a2 * innorm, v3 = a3 * innorm;
    float v4 = a4 * innorm, v5 = a5 * innorm, v6 = a6 * innorm, v7 = a7 * innorm;

    if (mode == 0) {
        if (p == 0) {
            float on = out_norm[node];
            uint4 w;
            w.x = (uint32_t)f2bf(v0 * on) | ((uint32_t)f2bf(v1 * on) << 16);
            w.y = (uint32_t)f2bf(v2 * on) | ((uint32_t)f2bf(v3 * on) << 16);
            w.z = (uint32_t)f2bf(v4 * on) | ((uint32_t)f2bf(v5 * on) << 16);
            w.w = (uint32_t)f2bf(v6 * on) | ((uint32_t)f2bf(v7 * on) << 16);
            hn128[node * 8 + q] = w;
        }
    } else {
        // final: res = x + (h1_own*s1 + h2_own*s2)*rinv + e3*s3
        if (p == 1 || p == 2) {
            int of = node * 16 + 2 * q + (p - 1);
            float4 x = (node < USER_NUM) ? user4[of] : item4[of - USER_NUM * 16];
            uint2 h1 = h1own[of];
            uint2 h2 = ((const uint2*)h32)[of];   // gather table IS h2
            float rinv = 1.0f / out_norm[node];   // = sqrt(out_deg)
            float b0 = (p == 1) ? v0 : v4;
            float b1 = (p == 1) ? v1 : v5;
            float b2 = (p == 1) ? v2 : v6;
            float b3 = (p == 1) ? v3 : v7;
            float4 rv;
            rv.x = x.x + (lo_bf(h1.x) * s1 + lo_bf(h2.x) * s2) * rinv + b0 * s3;
            rv.y = x.y + (hi_bf(h1.x) * s1 + hi_bf(h2.x) * s2) * rinv + b1 * s3;
            rv.z = x.z + (lo_bf(h1.y) * s1 + lo_bf(h2.y) * s2) * rinv + b2 * s3;
            rv.w = x.w + (hi_bf(h1.y) * s1 + hi_bf(h2.y) * s2) * rinv + b3 * s3;
            res4[of] = rv;
        }
    }
}

static inline uintptr_t align_up(uintptr_t p, uintptr_t a) { return (p + a - 1) & ~(a - 1); }

extern "C" void kernel_launch(void* const* d_in, const int* in_sizes, int n_in,
                              void* d_out, int out_size, void* d_ws, size_t ws_size,
                              hipStream_t stream) {
    const float* user_emb = (const float*)d_in[0];
    const float* item_emb = (const float*)d_in[1];
    const int*   src      = (const int*)d_in[2];
    const int*   dst      = (const int*)d_in[3];
    float*       res      = (float*)d_out;

    // ---- workspace layout (~57 MB with lifetime aliasing) ----
    uintptr_t p = (uintptr_t)d_ws;
    int* in_cnt = (int*)p;                     p = align_up(p + (size_t)N_NODES * 4, 128);
    float* out_norm = (float*)p;               p = align_up(p + (size_t)N_NODES * 4, 128);
    float* in_norm = (float*)p;                p = align_up(p + (size_t)N_NODES * 4, 128);
    uint32_t* rowptr = (uint32_t*)p;           p = align_up(p + (size_t)N_NODES * 4, 128);
    uint32_t* btot = (uint32_t*)p;             p = align_up(p + (size_t)(2 * NBUCK) * 4, 128);
    uint32_t* bbase = (uint32_t*)p;            p = align_up(p + (size_t)(NBUCK + 1) * 4, 128);
    int* esrc = (int*)p;                       p = align_up(p + (size_t)N_EDGES * 4, 128);  // 16MB CSR
    uint32_t* hA = (uint32_t*)p;               p = align_up(p + (size_t)N_NODES * 32 * 4, 128); // 19.2MB
    uint32_t* hB = (uint32_t*)p;
    uint32_t* gcur = btot + NBUCK;             // zeroed together with btot
    // lifetime aliases:
    //   sorted (16MB) lives in hA      (dead after slabinit; h1 written there by agg L0)
    //   out-deg partial (19.2MB) in hB (dead after rednorm; h0 written there by slabinit's
    //                                   init sub-blocks -- NOT hA, slab still reads sorted)
    uint32_t* sorted  = hA;
    uint32_t* partial = hB;

    const int BT = 256;
    int ab = (N_NODES / 2 * 64 + BT - 1) / BT;   // 2 nodes per wave

    const float2* user2 = (const float2*)user_emb;
    const float2* item2 = (const float2*)item_emb;
    const float4* user4 = (const float4*)user_emb;
    const float4* item4 = (const float4*)item_emb;

    hipMemsetAsync(btot, 0, (size_t)(2 * NBUCK) * 4, stream);
    histfused_kernel<<<(HRANGES + 1) * SLICES, 512, 0, stream>>>(src, dst, partial, btot);
    rednorm_kernel<<<NRB + 1, 512, 0, stream>>>(partial, out_norm, btot, bbase);
    scatter_kernel<<<SSLICES, 512, 0, stream>>>(src, dst, bbase, gcur, sorted);
    slabinit_kernel<<<NBUCK + INIT_BLOCKS, 512, 0, stream>>>(
        sorted, btot, bbase, esrc, in_cnt, in_norm, rowptr, user2, item2, out_norm, hB);

    // L0: gather h0(hB) -> pack h1(hA)   (sorted in hA is dead after slabinit)
    agg_kernel<<<ab, BT, 0, stream>>>(hB, esrc, rowptr, in_cnt, in_norm, out_norm, user4, item4,
                                      (float4*)res, (uint4*)hA, (const uint2*)hA,
                                      0.0f, 0.0f, 0.0f, 0);
    // L1: gather h1(hA) -> pack h2(hB)   (h0 dead)
    agg_kernel<<<ab, BT, 0, stream>>>(hA, esrc, rowptr, in_cnt, in_norm, out_norm, user4, item4,
                                      (float4*)res, (uint4*)hB, (const uint2*)hA,
                                      0.0f, 0.0f, 0.0f, 0);
    // L2/final: gather h2(hB); res = x + (h1*1/2 + h2*1/3)*rinv + e3*1/4  (h1own = hA)
    agg_kernel<<<ab, BT, 0, stream>>>(hB, esrc, rowptr, in_cnt, in_norm, out_norm, user4, item4,
                                      (float4*)res, (uint4*)hA, (const uint2*)hA,
                                      0.5f, 1.0f / 3.0f, 0.25f, 1);
}

// Round 9
// 412.740 us; speedup vs baseline: 1.0439x; 1.0004x over previous
//
#include <hip/hip_runtime.h>
#include <stdint.h>

#define USER_NUM 100000
#define ITEM_NUM 50000
#define N_NODES  150000
#define HIDE_DIM 64
#define N_EDGES  4000000

// ---- out-degree histogram (atomic-free, 8-bit packed LDS bins) ----
#define HRANGES 2
#define RNODES  75000
#define RWORDS  (RNODES / 4)           // 18750 words = 75 KB bins
#define SLICES  128                    // 4M % 128 == 0 -> EPS exact
#define EPS     (N_EDGES / SLICES)     // 31250
#define NRB     ((HRANGES * RWORDS + 511) / 512)   // 74 rednorm blocks; block NRB = btot scan

// ---- bucket sort by dst ----
#define BSH     9
#define BNODES  512
#define NBUCK   293                    // ceil(150000/512)
#define SSLICES 640                    // scatter slices; 5 per hist dst-block (640 = 5*128)
#define EPSB    (N_EDGES / SSLICES)    // 6250, exact; EPS = 5*EPSB
#define NSUB    (EPS / EPSB)           // 5 sub-slices per dst-hist block

// ---- slab CSR staging ----
#define STAGE_CAP 15000                // max bucket edges staged in LDS (binomial max ~14.1k)
#define INIT_BLOCKS ((N_NODES * 32) / 512)   // 9375, exact

// ---- bf16 helpers ----
__device__ __forceinline__ unsigned short f2bf(float f) {
    union { float f; unsigned int i; } c; c.f = f;
    unsigned int b = c.i;
    return (unsigned short)((b + 0x7FFFu + ((b >> 16) & 1u)) >> 16);
}
__device__ __forceinline__ float lo_bf(uint32_t u) {
    union { uint32_t u; float f; } c; c.u = u << 16; return c.f;
}
__device__ __forceinline__ float hi_bf(uint32_t u) {
    union { uint32_t u; float f; } c; c.u = u & 0xffff0000u; return c.f;
}

// ---------------- fused histograms ----------------
// blocks r in [0,2): out-degree partial hist of src for 75k-node range r (8-bit packed bins,
//                    75 KB LDS -> src read only 2x instead of 3x)
// blocks r == 2   : dst bucket hist at sub-slice granularity -> cntA[640][293] rows
//                    (consumed by scatter, which then skips its count pass) + btot atomics
__global__ __launch_bounds__(512) void histfused_kernel(
        const int* __restrict__ src, const int* __restrict__ dst,
        uint32_t* __restrict__ partial, uint32_t* __restrict__ btot,
        uint32_t* __restrict__ cntA) {
    __shared__ uint32_t bins[RWORDS];   // 75 KB; r==2 uses first NSUB*NBUCK words
    int r  = blockIdx.x / SLICES;
    int sl = blockIdx.x - r * SLICES;
    int e0 = sl * EPS, e1 = e0 + EPS;   // exact slicing
    if (r < HRANGES) {
        for (int i = threadIdx.x; i < RWORDS; i += 512) bins[i] = 0;
        __syncthreads();
        int lo = r * RNODES, hi = lo + RNODES;
        for (int e = e0 + threadIdx.x; e < e1; e += 512) {
            int s = src[e];
            if (s >= lo && s < hi) {
                int x = s - lo;
                atomicAdd(&bins[x >> 2], 1u << (8 * (x & 3)));
            }
        }
        __syncthreads();
        uint32_t* out = partial + (size_t)(r * SLICES + sl) * RWORDS;
        for (int i = threadIdx.x; i < RWORDS; i += 512) out[i] = bins[i];
    } else {
        for (int i = threadIdx.x; i < NSUB * NBUCK; i += 512) bins[i] = 0;
        __syncthreads();
        for (int e = e0 + threadIdx.x; e < e1; e += 512) {
            int sub = (e - e0) / EPSB;
            atomicAdd(&bins[sub * NBUCK + (((unsigned)dst[e]) >> BSH)], 1u);
        }
        __syncthreads();
        for (int i = threadIdx.x; i < NBUCK; i += 512) {
            uint32_t tot = 0;
#pragma unroll
            for (int sub = 0; sub < NSUB; ++sub) {
                uint32_t c = bins[sub * NBUCK + i];
                cntA[(size_t)(sl * NSUB + sub) * NBUCK + i] = c;
                tot += c;
            }
            if (tot) atomicAdd(&btot[i], tot);
        }
    }
}

// ---------------- reduce out-degree partials -> out_norm; last block: scan btot -> bbase ----------
__global__ void rednorm_kernel(const uint32_t* __restrict__ partial, float* __restrict__ out_norm,
                               const uint32_t* __restrict__ btot, uint32_t* __restrict__ bbase) {
    if (blockIdx.x == NRB) {
        __shared__ uint32_t tot[512];
        int t = threadIdx.x;
        uint32_t v = (t < NBUCK) ? btot[t] : 0;
        tot[t] = v;
        __syncthreads();
        for (int off = 1; off < 512; off <<= 1) {
            uint32_t x = (t >= off) ? tot[t - off] : 0;
            __syncthreads();
            tot[t] += x;
            __syncthreads();
        }
        if (t < NBUCK) bbase[t] = tot[t] - v;
        if (t == NBUCK - 1) bbase[NBUCK] = tot[t];
        return;
    }
    int g = blockIdx.x * 512 + threadIdx.x;
    if (g >= HRANGES * RWORDS) return;
    int r = g / RWORDS, w = g - r * RWORDS;
    const uint32_t* p = partial + (size_t)r * SLICES * RWORDS + w;
    uint32_t acc = 0;
#pragma unroll 16
    for (int sl = 0; sl < SLICES; ++sl) acc += p[(size_t)sl * RWORDS];
    int oc0 = acc & 255, oc1 = (acc >> 8) & 255, oc2 = (acc >> 16) & 255, oc3 = (acc >> 24);
    float4 o;
    o.x = 1.0f / sqrtf((float)(oc0 < 1 ? 1 : oc0));
    o.y = 1.0f / sqrtf((float)(oc1 < 1 ? 1 : oc1));
    o.z = 1.0f / sqrtf((float)(oc2 < 1 ? 1 : oc2));
    o.w = 1.0f / sqrtf((float)(oc3 < 1 ? 1 : oc3));
    ((float4*)out_norm)[(size_t)r * RWORDS + w] = o;
}

// ---------------- scatter v7: count row precomputed by histfused -> single edge pass ----------
__global__ __launch_bounds__(512) void scatter_kernel(
        const int* __restrict__ src, const int* __restrict__ dst,
        const uint32_t* __restrict__ cntA, const uint32_t* __restrict__ bbase,
        uint32_t* __restrict__ gcur, uint32_t* __restrict__ sorted) {
    __shared__ uint32_t cnt[NBUCK];    // cursor (starts at local exclusive offset)
    __shared__ uint32_t excl[NBUCK];   // local exclusive scan
    __shared__ uint32_t gpos0[NBUCK];  // reserved global run start per bucket
    __shared__ uint32_t sarr[512];     // scan workspace
    __shared__ uint32_t sval[EPSB];    // staged packed values, bucket-grouped (25 KB)
    __shared__ uint16_t sbkt[EPSB];    // bucket id per staged entry (12.5 KB)

    int s = blockIdx.x;
    int t = threadIdx.x;

    // load this slice's bucket counts (histfused already counted them)
    uint32_t myc = (t < NBUCK) ? cntA[(size_t)s * NBUCK + t] : 0;
    sarr[t] = myc;
    __syncthreads();
    for (int off = 1; off < 512; off <<= 1) {
        uint32_t x = (t >= off) ? sarr[t - off] : 0;
        __syncthreads();
        sarr[t] += x;
        __syncthreads();
    }
    if (t < NBUCK) {
        uint32_t ex = sarr[t] - myc;
        excl[t] = ex;
        cnt[t] = ex;                                              // local cursor starts at excl
        if (myc) gpos0[t] = bbase[t] + atomicAdd(&gcur[t], myc);  // reserve contiguous run
    }
    __syncthreads();

    // single edge pass: place into LDS grouped by bucket, tag with bucket id
    int e0 = s * EPSB;
    for (int e = e0 + t; e < e0 + EPSB; e += 512) {
        unsigned d = (unsigned)dst[e];
        int sv = src[e];
        unsigned b = d >> BSH;
        unsigned nib = d & (BNODES - 1);
        uint32_t r = atomicAdd(&cnt[b], 1u);
        sval[r] = (uint32_t)sv | (nib << 18);
        sbkt[r] = (uint16_t)b;
    }
    __syncthreads();

    // stream out (coalesced within bucket runs)
    for (int i = t; i < EPSB; i += 512) {
        unsigned b = sbkt[i];
        sorted[gpos0[b] + ((uint32_t)i - excl[b])] = sval[i];
    }
}

// ---------------- slab v3 + init fused ----------------
// blocks [0, NBUCK): CSR slab build. Per bucket: count pass -> in_cnt/in_norm + local
//   prefix -> rowptr (= bbase[b] + excl); pass 2 builds the COMPACT bucket image in LDS
//   (<= 60 KB) and streams it out fully coalesced. Fallback if bucket > STAGE_CAP.
// blocks [NBUCK, NBUCK+INIT_BLOCKS): init h0 = bf16(x * out_norm) -> hB (partial is dead;
//   h0 CANNOT live in hA because slab blocks of this same kernel still read sorted there).
__global__ __launch_bounds__(512) void slabinit_kernel(
        const uint32_t* __restrict__ sorted, const uint32_t* __restrict__ btot,
        const uint32_t* __restrict__ bbase,
        int* __restrict__ esrc, int* __restrict__ in_cnt, float* __restrict__ in_norm,
        uint32_t* __restrict__ rowptr,
        const float2* __restrict__ user2, const float2* __restrict__ item2,
        const float* __restrict__ out_norm, uint32_t* __restrict__ h0) {
    int t = threadIdx.x;
    if (blockIdx.x >= NBUCK) {
        int gid = (blockIdx.x - NBUCK) * 512 + t;
        if (gid < N_NODES * 32) {
            int node = gid >> 5;
            float2 v = (node < USER_NUM) ? user2[gid] : item2[gid - USER_NUM * 32];
            float on = out_norm[node];
            h0[gid] = (uint32_t)f2bf(v.x * on) | ((uint32_t)f2bf(v.y * on) << 16);
        }
        return;
    }
    __shared__ uint32_t cnt[BNODES];
    __shared__ uint32_t sarr[BNODES];
    __shared__ int stage[STAGE_CAP];    // 60 KB
    int b = blockIdx.x;
    uint32_t start = bbase[b];
    uint32_t n = btot[b];
    cnt[t] = 0;
    __syncthreads();

    // pass 0: per-node counts
    for (uint32_t i = t; i < n; i += 512)
        atomicAdd(&cnt[sorted[start + i] >> 18], 1u);
    __syncthreads();

    // scan 512 node counts -> local exclusive prefix
    uint32_t v = cnt[t];
    sarr[t] = v;
    __syncthreads();
    for (int off = 1; off < 512; off <<= 1) {
        uint32_t x = (t >= off) ? sarr[t - off] : 0;
        __syncthreads();
        sarr[t] += x;
        __syncthreads();
    }
    uint32_t excl = sarr[t] - v;
    int node = (b << BSH) + t;
    if (node < N_NODES) {
        rowptr[node] = start + excl;
        in_cnt[node] = (int)v;
        in_norm[node] = 1.0f / sqrtf((float)(v < 1 ? 1 : v));
    }
    cnt[t] = excl;          // cursor starts at local exclusive offset
    __syncthreads();

    if (n <= STAGE_CAP) {
        // pass 2: build compact image in LDS, stream out coalesced
        for (uint32_t i = t; i < n; i += 512) {
            uint32_t w = sorted[start + i];
            uint32_t r = atomicAdd(&cnt[w >> 18], 1u);
            stage[r] = (int)(w & 0x3FFFFu);
        }
        __syncthreads();
        for (uint32_t i = t; i < n; i += 512) esrc[start + i] = stage[i];
    } else {
        // fallback (statistically unreachable): scattered but correct
        for (uint32_t i = t; i < n; i += 512) {
            uint32_t w = sorted[start + i];
            uint32_t r = atomicAdd(&cnt[w >> 18], 1u);
            esrc[start + r] = (int)(w & 0x3FFFFu);
        }
    }
}

// ---------------- gather aggregation v10: core FROZEN; CSR addressing ----------------
// lane = (half = node [bit5], p = edge parity [bits3-4], q = 16B col [bits0-2]).
// mode 0 (L0, L1): hn = pack(emb*on)                       [pure pack, no res traffic]
// mode 1 (L2/final): res = x + (h1_own*s1 + h2_own*s2)*rinv + e3*s3
__global__ void agg_kernel(const uint32_t* __restrict__ h32, const int* __restrict__ esrc,
                           const uint32_t* __restrict__ rowptr, const int* __restrict__ in_cnt,
                           const float* __restrict__ in_norm, const float* __restrict__ out_norm,
                           const float4* __restrict__ user4, const float4* __restrict__ item4,
                           float4* __restrict__ res4, uint4* __restrict__ hn128,
                           const uint2* __restrict__ h1own,
                           float s1, float s2, float s3, int mode) {
    int wid  = (blockIdx.x * blockDim.x + threadIdx.x) >> 6;
    int lane = threadIdx.x & 63;
    int half = lane >> 5;
    int p    = (lane >> 3) & 3;
    int q    = lane & 7;
    int node = wid * 2 + half;
    if (node >= N_NODES) return;

    int deg = in_cnt[node];
    int beg = (int)rowptr[node];          // CSR: exact, no clipping
    int hb  = half << 5;

    // half-lane l holds edge l in idx0 and edge 32+l in idx1 (masked to 0 if OOR)
    int sl0 = lane & 31;
    int idx0 = (sl0      < deg) ? esrc[beg + sl0]      : 0;
    int idx1 = (sl0 + 32 < deg) ? esrc[beg + sl0 + 32] : 0;

    const uint4* h128 = (const uint4*)h32;   // 8 x uint4 per node (128B)

    float a0 = 0.f, a1 = 0.f, a2 = 0.f, a3 = 0.f;
    float a4 = 0.f, a5 = 0.f, a6 = 0.f, a7 = 0.f;

#define ACC8(U) do { \
        a0 += lo_bf((U).x); a1 += hi_bf((U).x); \
        a2 += lo_bf((U).y); a3 += hi_bf((U).y); \
        a4 += lo_bf((U).z); a5 += hi_bf((U).z); \
        a6 += lo_bf((U).w); a7 += hi_bf((U).w); } while (0)

    // ---- stage 0: edges [0, min(deg,32)), parity p owns e = 4j + p, j = 0..7 ----
    int d0 = (deg < 32) ? deg : 32;
    {
        int sA0 = __shfl(idx0, hb + p,      64);
        int sA1 = __shfl(idx0, hb + 4 + p,  64);
        int sA2 = __shfl(idx0, hb + 8 + p,  64);
        int sA3 = __shfl(idx0, hb + 12 + p, 64);
        uint4 uA0 = h128[sA0 * 8 + q];
        uint4 uA1 = h128[sA1 * 8 + q];
        uint4 uA2 = h128[sA2 * 8 + q];
        uint4 uA3 = h128[sA3 * 8 + q];
        int sB0 = __shfl(idx0, hb + 16 + p, 64);
        int sB1 = __shfl(idx0, hb + 20 + p, 64);
        int sB2 = __shfl(idx0, hb + 24 + p, 64);
        int sB3 = __shfl(idx0, hb + 28 + p, 64);
        uint4 uB0 = h128[sB0 * 8 + q];
        uint4 uB1 = h128[sB1 * 8 + q];
        uint4 uB2 = h128[sB2 * 8 + q];
        uint4 uB3 = h128[sB3 * 8 + q];
        if (p      < d0) ACC8(uA0);
        if (4 + p  < d0) ACC8(uA1);
        if (8 + p  < d0) ACC8(uA2);
        if (12 + p < d0) ACC8(uA3);
        if (16 + p < d0) ACC8(uB0);
        if (20 + p < d0) ACC8(uB1);
        if (24 + p < d0) ACC8(uB2);
        if (28 + p < d0) ACC8(uB3);
    }

    // ---- stage 1: edges [32, min(deg,64)) via idx1, local e' = e-32 in [0, m1) ----
    int m1 = ((deg < 64) ? deg : 64) - 32;
    if (m1 > 0) {
        int nj1 = (m1 + 3) >> 2;
        int j = 0;
        for (; 4 * j + 8 <= m1; j += 2) {
            int e0 = 4 * j + p;
            int s0 = __shfl(idx1, hb + e0,     64);
            int s1g = __shfl(idx1, hb + e0 + 4, 64);
            uint4 u0 = h128[s0 * 8 + q];
            uint4 u1 = h128[s1g * 8 + q];
            ACC8(u0);
            ACC8(u1);
        }
        for (; j < nj1; ++j) {
            int e = 4 * j + p;
            int s = __shfl(idx1, hb + e, 64);
            uint4 u = h128[s * 8 + q];
            if (e < m1) ACC8(u);
        }
    }

    // ---- rare tail: edges [64, deg), direct loads (no shfl -> divergence-safe) ----
    for (int e = 64 + p; e < deg; e += 4) {
        int s = esrc[beg + e];
        uint4 u = h128[s * 8 + q];
        ACC8(u);
    }
#undef ACC8

    // combine 4 parities (xor 8 flips p bit0, xor 16 flips p bit1; stays within half)
    a0 += __shfl_xor(a0, 8, 64);  a1 += __shfl_xor(a1, 8, 64);
    a2 += __shfl_xor(a2, 8, 64);  a3 += __shfl_xor(a3, 8, 64);
    a4 += __shfl_xor(a4, 8, 64);  a5 += __shfl_xor(a5, 8, 64);
    a6 += __shfl_xor(a6, 8, 64);  a7 += __shfl_xor(a7, 8, 64);
    a0 += __shfl_xor(a0, 16, 64); a1 += __shfl_xor(a1, 16, 64);
    a2 += __shfl_xor(a2, 16, 64); a3 += __shfl_xor(a3, 16, 64);
    a4 += __shfl_xor(a4, 16, 64); a5 += __shfl_xor(a5, 16, 64);
    a6 += __shfl_xor(a6, 16, 64); a7 += __shfl_xor(a7, 16, 64);

    float innorm = in_norm[node];
    float v0 = a0 * innorm, v1 = a1 * innorm, v2 = a2 * innorm, v3 = a3 * innorm;
    float v4 = a4 * innorm, v5 = a5 * innorm, v6 = a6 * innorm, v7 = a7 * innorm;

    if (mode == 0) {
        if (p == 0) {
            float on = out_norm[node];
            uint4 w;
            w.x = (uint32_t)f2bf(v0 * on) | ((uint32_t)f2bf(v1 * on) << 16);
            w.y = (uint32_t)f2bf(v2 * on) | ((uint32_t)f2bf(v3 * on) << 16);
            w.z = (uint32_t)f2bf(v4 * on) | ((uint32_t)f2bf(v5 * on) << 16);
            w.w = (uint32_t)f2bf(v6 * on) | ((uint32_t)f2bf(v7 * on) << 16);
            hn128[node * 8 + q] = w;
        }
    } else {
        // final: res = x + (h1_own*s1 + h2_own*s2)*rinv + e3*s3
        if (p == 1 || p == 2) {
            int of = node * 16 + 2 * q + (p - 1);
            float4 x = (node < USER_NUM) ? user4[of] : item4[of - USER_NUM * 16];
            uint2 h1 = h1own[of];
            uint2 h2 = ((const uint2*)h32)[of];   // gather table IS h2
            float rinv = 1.0f / out_norm[node];   // = sqrt(out_deg)
            float b0 = (p == 1) ? v0 : v4;
            float b1 = (p == 1) ? v1 : v5;
            float b2 = (p == 1) ? v2 : v6;
            float b3 = (p == 1) ? v3 : v7;
            float4 rv;
            rv.x = x.x + (lo_bf(h1.x) * s1 + lo_bf(h2.x) * s2) * rinv + b0 * s3;
            rv.y = x.y + (hi_bf(h1.x) * s1 + hi_bf(h2.x) * s2) * rinv + b1 * s3;
            rv.z = x.z + (lo_bf(h1.y) * s1 + lo_bf(h2.y) * s2) * rinv + b2 * s3;
            rv.w = x.w + (hi_bf(h1.y) * s1 + hi_bf(h2.y) * s2) * rinv + b3 * s3;
            res4[of] = rv;
        }
    }
}

static inline uintptr_t align_up(uintptr_t p, uintptr_t a) { return (p + a - 1) & ~(a - 1); }

extern "C" void kernel_launch(void* const* d_in, const int* in_sizes, int n_in,
                              void* d_out, int out_size, void* d_ws, size_t ws_size,
                              hipStream_t stream) {
    const float* user_emb = (const float*)d_in[0];
    const float* item_emb = (const float*)d_in[1];
    const int*   src      = (const int*)d_in[2];
    const int*   dst      = (const int*)d_in[3];
    float*       res      = (float*)d_out;

    // ---- workspace layout (~57 MB with lifetime aliasing) ----
    uintptr_t p = (uintptr_t)d_ws;
    int* in_cnt = (int*)p;                     p = align_up(p + (size_t)N_NODES * 4, 128);
    float* out_norm = (float*)p;               p = align_up(p + (size_t)N_NODES * 4, 128);
    float* in_norm = (float*)p;                p = align_up(p + (size_t)N_NODES * 4, 128);
    uint32_t* rowptr = (uint32_t*)p;           p = align_up(p + (size_t)N_NODES * 4, 128);
    uint32_t* btot = (uint32_t*)p;             p = align_up(p + (size_t)(2 * NBUCK) * 4, 128);
    uint32_t* bbase = (uint32_t*)p;            p = align_up(p + (size_t)(NBUCK + 1) * 4, 128);
    int* esrc = (int*)p;                       p = align_up(p + (size_t)N_EDGES * 4, 128);  // 16MB CSR
    uint32_t* hA = (uint32_t*)p;               p = align_up(p + (size_t)N_NODES * 32 * 4, 128); // 19.2MB
    uint32_t* hB = (uint32_t*)p;
    uint32_t* gcur = btot + NBUCK;             // zeroed together with btot
    // lifetime aliases:
    //   sorted (16MB) lives in hA      (dead after slabinit; h1 written there by agg L0)
    //   out-deg partial (19.2MB = 2*128*18750 words) in hB (dead after rednorm; h0 written
    //                                   there by slabinit's init sub-blocks)
    //   cntA (750KB = 640*293 words) in esrc front (consumed by scatter BEFORE slabinit
    //                                   writes esrc)
    uint32_t* sorted  = hA;
    uint32_t* partial = hB;
    uint32_t* cntA    = (uint32_t*)esrc;

    const int BT = 256;
    int ab = (N_NODES / 2 * 64 + BT - 1) / BT;   // 2 nodes per wave

    const float2* user2 = (const float2*)user_emb;
    const float2* item2 = (const float2*)item_emb;
    const float4* user4 = (const float4*)user_emb;
    const float4* item4 = (const float4*)item_emb;

    hipMemsetAsync(btot, 0, (size_t)(2 * NBUCK) * 4, stream);
    histfused_kernel<<<(HRANGES + 1) * SLICES, 512, 0, stream>>>(src, dst, partial, btot, cntA);
    rednorm_kernel<<<NRB + 1, 512, 0, stream>>>(partial, out_norm, btot, bbase);
    scatter_kernel<<<SSLICES, 512, 0, stream>>>(src, dst, cntA, bbase, gcur, sorted);
    slabinit_kernel<<<NBUCK + INIT_BLOCKS, 512, 0, stream>>>(
        sorted, btot, bbase, esrc, in_cnt, in_norm, rowptr, user2, item2, out_norm, hB);

    // L0: gather h0(hB) -> pack h1(hA)   (sorted in hA is dead after slabinit)
    agg_kernel<<<ab, BT, 0, stream>>>(hB, esrc, rowptr, in_cnt, in_norm, out_norm, user4, item4,
                                      (float4*)res, (uint4*)hA, (const uint2*)hA,
                                      0.0f, 0.0f, 0.0f, 0);
    // L1: gather h1(hA) -> pack h2(hB)   (h0 dead)
    agg_kernel<<<ab, BT, 0, stream>>>(hA, esrc, rowptr, in_cnt, in_norm, out_norm, user4, item4,
                                      (float4*)res, (uint4*)hB, (const uint2*)hA,
                                      0.0f, 0.0f, 0.0f, 0);
    // L2/final: gather h2(hB); res = x + (h1*1/2 + h2*1/3)*rinv + e3*1/4  (h1own = hA)
    agg_kernel<<<ab, BT, 0, stream>>>(hB, esrc, rowptr, in_cnt, in_norm, out_norm, user4, item4,
                                      (float4*)res, (uint4*)hA, (const uint2*)hA,
                                      0.5f, 1.0f / 3.0f, 0.25f, 1);
}

// Round 10
// 381.007 us; speedup vs baseline: 1.1308x; 1.0833x over previous
//
#include <hip/hip_runtime.h>
#include <stdint.h>

#define USER_NUM 100000
#define ITEM_NUM 50000
#define N_NODES  150000
#define HIDE_DIM 64
#define N_EDGES  4000000

// ---- out-degree histogram (atomic-free, 8-bit packed LDS bins) ----
#define HRANGES 2
#define RNODES  75000
#define RWORDS  (RNODES / 4)           // 18750 words = 75 KB bins
#define SLICES  128                    // 4M % 128 == 0 -> EPS exact
#define EPS     (N_EDGES / SLICES)     // 31250
#define NRB     ((HRANGES * RWORDS + 511) / 512)   // 74 rednorm blocks; block NRB = btot scan

// ---- bucket sort by dst ----
#define BSH     9
#define BNODES  512
#define NBUCK   293                    // ceil(150000/512)
#define SSLICES 640                    // scatter slices; 5 per hist dst-block (640 = 5*128)
#define EPSB    (N_EDGES / SSLICES)    // 6250, exact; EPS = 5*EPSB
#define NSUB    (EPS / EPSB)           // 5 sub-slices per dst-hist block

// ---- slab CSR staging ----
#define STAGE_CAP 15000                // max bucket edges staged in LDS (binomial max ~14.1k)
#define INIT_BLOCKS ((N_NODES * 32 + 1023) / 1024)   // 4688 @ 1024 thr

// ---- bf16 helpers ----
__device__ __forceinline__ unsigned short f2bf(float f) {
    union { float f; unsigned int i; } c; c.f = f;
    unsigned int b = c.i;
    return (unsigned short)((b + 0x7FFFu + ((b >> 16) & 1u)) >> 16);
}
__device__ __forceinline__ float lo_bf(uint32_t u) {
    union { uint32_t u; float f; } c; c.u = u << 16; return c.f;
}
__device__ __forceinline__ float hi_bf(uint32_t u) {
    union { uint32_t u; float f; } c; c.u = u & 0xffff0000u; return c.f;
}

// ---------------- fused histograms (1024 thr: 75 KB LDS x 2 blocks/CU = 32 waves, full occ) ----
// blocks r in [0,2): out-degree partial hist of src for 75k-node range r (8-bit packed bins)
// blocks r == 2   : dst bucket hist at sub-slice granularity -> cntA[640][293] rows
//                    (consumed by scatter, which then skips its count pass) + btot atomics
__global__ __launch_bounds__(1024) void histfused_kernel(
        const int* __restrict__ src, const int* __restrict__ dst,
        uint32_t* __restrict__ partial, uint32_t* __restrict__ btot,
        uint32_t* __restrict__ cntA) {
    __shared__ uint32_t bins[RWORDS];   // 75 KB; r==2 uses first NSUB*NBUCK words
    int r  = blockIdx.x / SLICES;
    int sl = blockIdx.x - r * SLICES;
    int e0 = sl * EPS, e1 = e0 + EPS;   // exact slicing
    if (r < HRANGES) {
        for (int i = threadIdx.x; i < RWORDS; i += 1024) bins[i] = 0;
        __syncthreads();
        int lo = r * RNODES, hi = lo + RNODES;
        for (int e = e0 + threadIdx.x; e < e1; e += 1024) {
            int s = src[e];
            if (s >= lo && s < hi) {
                int x = s - lo;
                atomicAdd(&bins[x >> 2], 1u << (8 * (x & 3)));
            }
        }
        __syncthreads();
        uint32_t* out = partial + (size_t)(r * SLICES + sl) * RWORDS;
        for (int i = threadIdx.x; i < RWORDS; i += 1024) out[i] = bins[i];
    } else {
        for (int i = threadIdx.x; i < NSUB * NBUCK; i += 1024) bins[i] = 0;
        __syncthreads();
        for (int e = e0 + threadIdx.x; e < e1; e += 1024) {
            int sub = (e - e0) / EPSB;
            atomicAdd(&bins[sub * NBUCK + (((unsigned)dst[e]) >> BSH)], 1u);
        }
        __syncthreads();
        for (int i = threadIdx.x; i < NBUCK; i += 1024) {
            uint32_t tot = 0;
#pragma unroll
            for (int sub = 0; sub < NSUB; ++sub) {
                uint32_t c = bins[sub * NBUCK + i];
                cntA[(size_t)(sl * NSUB + sub) * NBUCK + i] = c;
                tot += c;
            }
            if (tot) atomicAdd(&btot[i], tot);
        }
    }
}

// ---------------- reduce out-degree partials -> out_norm; last block: scan btot -> bbase ----------
__global__ void rednorm_kernel(const uint32_t* __restrict__ partial, float* __restrict__ out_norm,
                               const uint32_t* __restrict__ btot, uint32_t* __restrict__ bbase) {
    if (blockIdx.x == NRB) {
        __shared__ uint32_t tot[512];
        int t = threadIdx.x;
        uint32_t v = (t < NBUCK) ? btot[t] : 0;
        tot[t] = v;
        __syncthreads();
        for (int off = 1; off < 512; off <<= 1) {
            uint32_t x = (t >= off) ? tot[t - off] : 0;
            __syncthreads();
            tot[t] += x;
            __syncthreads();
        }
        if (t < NBUCK) bbase[t] = tot[t] - v;
        if (t == NBUCK - 1) bbase[NBUCK] = tot[t];
        return;
    }
    int g = blockIdx.x * 512 + threadIdx.x;
    if (g >= HRANGES * RWORDS) return;
    int r = g / RWORDS, w = g - r * RWORDS;
    const uint32_t* p = partial + (size_t)r * SLICES * RWORDS + w;
    uint32_t acc = 0;
#pragma unroll 16
    for (int sl = 0; sl < SLICES; ++sl) acc += p[(size_t)sl * RWORDS];
    int oc0 = acc & 255, oc1 = (acc >> 8) & 255, oc2 = (acc >> 16) & 255, oc3 = (acc >> 24);
    float4 o;
    o.x = 1.0f / sqrtf((float)(oc0 < 1 ? 1 : oc0));
    o.y = 1.0f / sqrtf((float)(oc1 < 1 ? 1 : oc1));
    o.z = 1.0f / sqrtf((float)(oc2 < 1 ? 1 : oc2));
    o.w = 1.0f / sqrtf((float)(oc3 < 1 ? 1 : oc3));
    ((float4*)out_norm)[(size_t)r * RWORDS + w] = o;
}

// ---------------- scatter v8 (1024 thr): precomputed counts -> single edge pass ----------
__global__ __launch_bounds__(1024) void scatter_kernel(
        const int* __restrict__ src, const int* __restrict__ dst,
        const uint32_t* __restrict__ cntA, const uint32_t* __restrict__ bbase,
        uint32_t* __restrict__ gcur, uint32_t* __restrict__ sorted) {
    __shared__ uint32_t cnt[NBUCK];    // cursor (starts at local exclusive offset)
    __shared__ uint32_t excl[NBUCK];   // local exclusive scan
    __shared__ uint32_t gpos0[NBUCK];  // reserved global run start per bucket
    __shared__ uint32_t sarr[512];     // scan workspace
    __shared__ uint32_t sval[EPSB];    // staged packed values, bucket-grouped (25 KB)
    __shared__ uint16_t sbkt[EPSB];    // bucket id per staged entry (12.5 KB)

    int s = blockIdx.x;
    int t = threadIdx.x;

    // load this slice's bucket counts (histfused already counted them); 512-wide scan
    uint32_t myc = 0;
    if (t < 512) {
        myc = (t < NBUCK) ? cntA[(size_t)s * NBUCK + t] : 0;
        sarr[t] = myc;
    }
    __syncthreads();
    for (int off = 1; off < 512; off <<= 1) {
        uint32_t x = 0;
        if (t < 512 && t >= off) x = sarr[t - off];
        __syncthreads();
        if (t < 512) sarr[t] += x;
        __syncthreads();
    }
    if (t < NBUCK) {
        uint32_t ex = sarr[t] - myc;
        excl[t] = ex;
        cnt[t] = ex;                                              // local cursor starts at excl
        if (myc) gpos0[t] = bbase[t] + atomicAdd(&gcur[t], myc);  // reserve contiguous run
    }
    __syncthreads();

    // single edge pass: place into LDS grouped by bucket, tag with bucket id
    int e0 = s * EPSB;
    for (int e = e0 + t; e < e0 + EPSB; e += 1024) {
        unsigned d = (unsigned)dst[e];
        int sv = src[e];
        unsigned b = d >> BSH;
        unsigned nib = d & (BNODES - 1);
        uint32_t r = atomicAdd(&cnt[b], 1u);
        sval[r] = (uint32_t)sv | (nib << 18);
        sbkt[r] = (uint16_t)b;
    }
    __syncthreads();

    // stream out (coalesced within bucket runs)
    for (int i = t; i < EPSB; i += 1024) {
        unsigned b = sbkt[i];
        sorted[gpos0[b] + ((uint32_t)i - excl[b])] = sval[i];
    }
}

// ---------------- slab v4 + init fused (1024 thr: 64 KB LDS x 2 blocks/CU = full occ) ----------
// blocks [0, NBUCK): CSR slab build. count pass -> in_cnt/in_norm + 512-wide prefix ->
//   rowptr; pass 2 builds the COMPACT bucket image in LDS (<= 60 KB), streams out
//   coalesced. Fallback if bucket > STAGE_CAP.
// blocks [NBUCK, ...): init h0 = bf16(x * out_norm) -> hB.
__global__ __launch_bounds__(1024) void slabinit_kernel(
        const uint32_t* __restrict__ sorted, const uint32_t* __restrict__ btot,
        const uint32_t* __restrict__ bbase,
        int* __restrict__ esrc, int* __restrict__ in_cnt, float* __restrict__ in_norm,
        uint32_t* __restrict__ rowptr,
        const float2* __restrict__ user2, const float2* __restrict__ item2,
        const float* __restrict__ out_norm, uint32_t* __restrict__ h0) {
    int t = threadIdx.x;
    if (blockIdx.x >= NBUCK) {
        int gid = (blockIdx.x - NBUCK) * 1024 + t;
        if (gid < N_NODES * 32) {
            int node = gid >> 5;
            float2 v = (node < USER_NUM) ? user2[gid] : item2[gid - USER_NUM * 32];
            float on = out_norm[node];
            h0[gid] = (uint32_t)f2bf(v.x * on) | ((uint32_t)f2bf(v.y * on) << 16);
        }
        return;
    }
    __shared__ uint32_t cnt[BNODES];
    __shared__ uint32_t sarr[BNODES];
    __shared__ int stage[STAGE_CAP];    // 60 KB
    int b = blockIdx.x;
    uint32_t start = bbase[b];
    uint32_t n = btot[b];
    if (t < BNODES) cnt[t] = 0;
    __syncthreads();

    // pass 0: per-node counts
    for (uint32_t i = t; i < n; i += 1024)
        atomicAdd(&cnt[sorted[start + i] >> 18], 1u);
    __syncthreads();

    // 512-wide scan of node counts -> local exclusive prefix (barriers unconditional)
    uint32_t v = 0;
    if (t < 512) { v = cnt[t]; sarr[t] = v; }
    __syncthreads();
    for (int off = 1; off < 512; off <<= 1) {
        uint32_t x = 0;
        if (t < 512 && t >= off) x = sarr[t - off];
        __syncthreads();
        if (t < 512) sarr[t] += x;
        __syncthreads();
    }
    if (t < 512) {
        uint32_t excl = sarr[t] - v;
        int node = (b << BSH) + t;
        if (node < N_NODES) {
            rowptr[node] = start + excl;
            in_cnt[node] = (int)v;
            in_norm[node] = 1.0f / sqrtf((float)(v < 1 ? 1 : v));
        }
        cnt[t] = excl;          // cursor starts at local exclusive offset
    }
    __syncthreads();

    if (n <= STAGE_CAP) {
        // pass 2: build compact image in LDS, stream out coalesced
        for (uint32_t i = t; i < n; i += 1024) {
            uint32_t w = sorted[start + i];
            uint32_t r = atomicAdd(&cnt[w >> 18], 1u);
            stage[r] = (int)(w & 0x3FFFFu);
        }
        __syncthreads();
        for (uint32_t i = t; i < n; i += 1024) esrc[start + i] = stage[i];
    } else {
        // fallback (statistically unreachable): scattered but correct
        for (uint32_t i = t; i < n; i += 1024) {
            uint32_t w = sorted[start + i];
            uint32_t r = atomicAdd(&cnt[w >> 18], 1u);
            esrc[start + r] = (int)(w & 0x3FFFFu);
        }
    }
}

// ---------------- gather aggregation v10: core FROZEN; CSR addressing ----------------
// lane = (half = node [bit5], p = edge parity [bits3-4], q = 16B col [bits0-2]).
// mode 0 (L0, L1): hn = pack(emb*on)                       [pure pack, no res traffic]
// mode 1 (L2/final): res = x + (h1_own*s1 + h2_own*s2)*rinv + e3*s3
__global__ void agg_kernel(const uint32_t* __restrict__ h32, const int* __restrict__ esrc,
                           const uint32_t* __restrict__ rowptr, const int* __restrict__ in_cnt,
                           const float* __restrict__ in_norm, const float* __restrict__ out_norm,
                           const float4* __restrict__ user4, const float4* __restrict__ item4,
                           float4* __restrict__ res4, uint4* __restrict__ hn128,
                           const uint2* __restrict__ h1own,
                           float s1, float s2, float s3, int mode) {
    int wid  = (blockIdx.x * blockDim.x + threadIdx.x) >> 6;
    int lane = threadIdx.x & 63;
    int half = lane >> 5;
    int p    = (lane >> 3) & 3;
    int q    = lane & 7;
    int node = wid * 2 + half;
    if (node >= N_NODES) return;

    int deg = in_cnt[node];
    int beg = (int)rowptr[node];          // CSR: exact, no clipping
    int hb  = half << 5;

    // half-lane l holds edge l in idx0 and edge 32+l in idx1 (masked to 0 if OOR)
    int sl0 = lane & 31;
    int idx0 = (sl0      < deg) ? esrc[beg + sl0]      : 0;
    int idx1 = (sl0 + 32 < deg) ? esrc[beg + sl0 + 32] : 0;

    const uint4* h128 = (const uint4*)h32;   // 8 x uint4 per node (128B)

    float a0 = 0.f, a1 = 0.f, a2 = 0.f, a3 = 0.f;
    float a4 = 0.f, a5 = 0.f, a6 = 0.f, a7 = 0.f;

#define ACC8(U) do { \
        a0 += lo_bf((U).x); a1 += hi_bf((U).x); \
        a2 += lo_bf((U).y); a3 += hi_bf((U).y); \
        a4 += lo_bf((U).z); a5 += hi_bf((U).z); \
        a6 += lo_bf((U).w); a7 += hi_bf((U).w); } while (0)

    // ---- stage 0: edges [0, min(deg,32)), parity p owns e = 4j + p, j = 0..7 ----
    int d0 = (deg < 32) ? deg : 32;
    {
        int sA0 = __shfl(idx0, hb + p,      64);
        int sA1 = __shfl(idx0, hb + 4 + p,  64);
        int sA2 = __shfl(idx0, hb + 8 + p,  64);
        int sA3 = __shfl(idx0, hb + 12 + p, 64);
        uint4 uA0 = h128[sA0 * 8 + q];
        uint4 uA1 = h128[sA1 * 8 + q];
        uint4 uA2 = h128[sA2 * 8 + q];
        uint4 uA3 = h128[sA3 * 8 + q];
        int sB0 = __shfl(idx0, hb + 16 + p, 64);
        int sB1 = __shfl(idx0, hb + 20 + p, 64);
        int sB2 = __shfl(idx0, hb + 24 + p, 64);
        int sB3 = __shfl(idx0, hb + 28 + p, 64);
        uint4 uB0 = h128[sB0 * 8 + q];
        uint4 uB1 = h128[sB1 * 8 + q];
        uint4 uB2 = h128[sB2 * 8 + q];
        uint4 uB3 = h128[sB3 * 8 + q];
        if (p      < d0) ACC8(uA0);
        if (4 + p  < d0) ACC8(uA1);
        if (8 + p  < d0) ACC8(uA2);
        if (12 + p < d0) ACC8(uA3);
        if (16 + p < d0) ACC8(uB0);
        if (20 + p < d0) ACC8(uB1);
        if (24 + p < d0) ACC8(uB2);
        if (28 + p < d0) ACC8(uB3);
    }

    // ---- stage 1: edges [32, min(deg,64)) via idx1, local e' = e-32 in [0, m1) ----
    int m1 = ((deg < 64) ? deg : 64) - 32;
    if (m1 > 0) {
        int nj1 = (m1 + 3) >> 2;
        int j = 0;
        for (; 4 * j + 8 <= m1; j += 2) {
            int e0 = 4 * j + p;
            int s0 = __shfl(idx1, hb + e0,     64);
            int s1g = __shfl(idx1, hb + e0 + 4, 64);
            uint4 u0 = h128[s0 * 8 + q];
            uint4 u1 = h128[s1g * 8 + q];
            ACC8(u0);
            ACC8(u1);
        }
        for (; j < nj1; ++j) {
            int e = 4 * j + p;
            int s = __shfl(idx1, hb + e, 64);
            uint4 u = h128[s * 8 + q];
            if (e < m1) ACC8(u);
        }
    }

    // ---- rare tail: edges [64, deg), direct loads (no shfl -> divergence-safe) ----
    for (int e = 64 + p; e < deg; e += 4) {
        int s = esrc[beg + e];
        uint4 u = h128[s * 8 + q];
        ACC8(u);
    }
#undef ACC8

    // combine 4 parities (xor 8 flips p bit0, xor 16 flips p bit1; stays within half)
    a0 += __shfl_xor(a0, 8, 64);  a1 += __shfl_xor(a1, 8, 64);
    a2 += __shfl_xor(a2, 8, 64);  a3 += __shfl_xor(a3, 8, 64);
    a4 += __shfl_xor(a4, 8, 64);  a5 += __shfl_xor(a5, 8, 64);
    a6 += __shfl_xor(a6, 8, 64);  a7 += __shfl_xor(a7, 8, 64);
    a0 += __shfl_xor(a0, 16, 64); a1 += __shfl_xor(a1, 16, 64);
    a2 += __shfl_xor(a2, 16, 64); a3 += __shfl_xor(a3, 16, 64);
    a4 += __shfl_xor(a4, 16, 64); a5 += __shfl_xor(a5, 16, 64);
    a6 += __shfl_xor(a6, 16, 64); a7 += __shfl_xor(a7, 16, 64);

    float innorm = in_norm[node];
    float v0 = a0 * innorm, v1 = a1 * innorm, v2 = a2 * innorm, v3 = a3 * innorm;
    float v4 = a4 * innorm, v5 = a5 * innorm, v6 = a6 * innorm, v7 = a7 * innorm;

    if (mode == 0) {
        if (p == 0) {
            float on = out_norm[node];
            uint4 w;
            w.x = (uint32_t)f2bf(v0 * on) | ((uint32_t)f2bf(v1 * on) << 16);
            w.y = (uint32_t)f2bf(v2 * on) | ((uint32_t)f2bf(v3 * on) << 16);
            w.z = (uint32_t)f2bf(v4 * on) | ((uint32_t)f2bf(v5 * on) << 16);
            w.w = (uint32_t)f2bf(v6 * on) | ((uint32_t)f2bf(v7 * on) << 16);
            hn128[node * 8 + q] = w;
        }
    } else {
        // final: res = x + (h1_own*s1 + h2_own*s2)*rinv + e3*s3
        if (p == 1 || p == 2) {
            int of = node * 16 + 2 * q + (p - 1);
            float4 x = (node < USER_NUM) ? user4[of] : item4[of - USER_NUM * 16];
            uint2 h1 = h1own[of];
            uint2 h2 = ((const uint2*)h32)[of];   // gather table IS h2
            float rinv = 1.0f / out_norm[node];   // = sqrt(out_deg)
            float b0 = (p == 1) ? v0 : v4;
            float b1 = (p == 1) ? v1 : v5;
            float b2 = (p == 1) ? v2 : v6;
            float b3 = (p == 1) ? v3 : v7;
            float4 rv;
            rv.x = x.x + (lo_bf(h1.x) * s1 + lo_bf(h2.x) * s2) * rinv + b0 * s3;
            rv.y = x.y + (hi_bf(h1.x) * s1 + hi_bf(h2.x) * s2) * rinv + b1 * s3;
            rv.z = x.z + (lo_bf(h1.y) * s1 + lo_bf(h2.y) * s2) * rinv + b2 * s3;
            rv.w = x.w + (hi_bf(h1.y) * s1 + hi_bf(h2.y) * s2) * rinv + b3 * s3;
            res4[of] = rv;
        }
    }
}

static inline uintptr_t align_up(uintptr_t p, uintptr_t a) { return (p + a - 1) & ~(a - 1); }

extern "C" void kernel_launch(void* const* d_in, const int* in_sizes, int n_in,
                              void* d_out, int out_size, void* d_ws, size_t ws_size,
                              hipStream_t stream) {
    const float* user_emb = (const float*)d_in[0];
    const float* item_emb = (const float*)d_in[1];
    const int*   src      = (const int*)d_in[2];
    const int*   dst      = (const int*)d_in[3];
    float*       res      = (float*)d_out;

    // ---- workspace layout (~57 MB with lifetime aliasing) ----
    uintptr_t p = (uintptr_t)d_ws;
    int* in_cnt = (int*)p;                     p = align_up(p + (size_t)N_NODES * 4, 128);
    float* out_norm = (float*)p;               p = align_up(p + (size_t)N_NODES * 4, 128);
    float* in_norm = (float*)p;                p = align_up(p + (size_t)N_NODES * 4, 128);
    uint32_t* rowptr = (uint32_t*)p;           p = align_up(p + (size_t)N_NODES * 4, 128);
    uint32_t* btot = (uint32_t*)p;             p = align_up(p + (size_t)(2 * NBUCK) * 4, 128);
    uint32_t* bbase = (uint32_t*)p;            p = align_up(p + (size_t)(NBUCK + 1) * 4, 128);
    int* esrc = (int*)p;                       p = align_up(p + (size_t)N_EDGES * 4, 128);  // 16MB CSR
    uint32_t* hA = (uint32_t*)p;               p = align_up(p + (size_t)N_NODES * 32 * 4, 128); // 19.2MB
    uint32_t* hB = (uint32_t*)p;
    uint32_t* gcur = btot + NBUCK;             // zeroed together with btot
    // lifetime aliases:
    //   sorted (16MB) lives in hA      (dead after slabinit; h1 written there by agg L0)
    //   out-deg partial (19.2MB) in hB (dead after rednorm; h0 written there by slabinit's
    //                                   init sub-blocks)
    //   cntA (750KB) in esrc front     (consumed by scatter BEFORE slabinit writes esrc)
    uint32_t* sorted  = hA;
    uint32_t* partial = hB;
    uint32_t* cntA    = (uint32_t*)esrc;

    const int BT = 256;
    int ab = (N_NODES / 2 * 64 + BT - 1) / BT;   // 2 nodes per wave

    const float2* user2 = (const float2*)user_emb;
    const float2* item2 = (const float2*)item_emb;
    const float4* user4 = (const float4*)user_emb;
    const float4* item4 = (const float4*)item_emb;

    hipMemsetAsync(btot, 0, (size_t)(2 * NBUCK) * 4, stream);
    histfused_kernel<<<(HRANGES + 1) * SLICES, 1024, 0, stream>>>(src, dst, partial, btot, cntA);
    rednorm_kernel<<<NRB + 1, 512, 0, stream>>>(partial, out_norm, btot, bbase);
    scatter_kernel<<<SSLICES, 1024, 0, stream>>>(src, dst, cntA, bbase, gcur, sorted);
    slabinit_kernel<<<NBUCK + INIT_BLOCKS, 1024, 0, stream>>>(
        sorted, btot, bbase, esrc, in_cnt, in_norm, rowptr, user2, item2, out_norm, hB);

    // L0: gather h0(hB) -> pack h1(hA)   (sorted in hA is dead after slabinit)
    agg_kernel<<<ab, BT, 0, stream>>>(hB, esrc, rowptr, in_cnt, in_norm, out_norm, user4, item4,
                                      (float4*)res, (uint4*)hA, (const uint2*)hA,
                                      0.0f, 0.0f, 0.0f, 0);
    // L1: gather h1(hA) -> pack h2(hB)   (h0 dead)
    agg_kernel<<<ab, BT, 0, stream>>>(hA, esrc, rowptr, in_cnt, in_norm, out_norm, user4, item4,
                                      (float4*)res, (uint4*)hB, (const uint2*)hA,
                                      0.0f, 0.0f, 0.0f, 0);
    // L2/final: gather h2(hB); res = x + (h1*1/2 + h2*1/3)*rinv + e3*1/4  (h1own = hA)
    agg_kernel<<<ab, BT, 0, stream>>>(hB, esrc, rowptr, in_cnt, in_norm, out_norm, user4, item4,
                                      (float4*)res, (uint4*)hA, (const uint2*)hA,
                                      0.5f, 1.0f / 3.0f, 0.25f, 1);
}